// Round 12
// baseline (1387.495 us; speedup 1.0000x reference)
//
#include <hip/hip_runtime.h>

#define NN 50000
#define NE 800000
#define NTILES 12500
#define TPB 10   // tiles (of 64 edges) per block; 12500 % 10 == 0 -> grid 1250

typedef __attribute__((ext_vector_type(8))) short short8;
typedef __attribute__((ext_vector_type(4))) float f32x4;

__device__ __forceinline__ float silu_f(float v) {
    return v / (1.0f + __expf(-v));
}
__device__ __forceinline__ unsigned short f2bf(float f) {
    unsigned u = __float_as_uint(f);
    u += 0x7fffu + ((u >> 16) & 1u);        // round-to-nearest-even
    return (unsigned short)(u >> 16);
}
__device__ __forceinline__ unsigned pk2(float a, float b) {
    return (unsigned)f2bf(a) | ((unsigned)f2bf(b) << 16);
}
__device__ __forceinline__ float bf2f(unsigned short v) {
    return __uint_as_float((unsigned)v << 16);
}
__device__ __forceinline__ void gload_lds16(const unsigned short* g, unsigned short* l) {
    __builtin_amdgcn_global_load_lds(
        (const __attribute__((address_space(1))) unsigned int*)g,
        (__attribute__((address_space(3))) unsigned int*)l, 16, 0, 0);
}
// lgkm-only barrier: drain LDS ops, leave vmcnt (in-flight gathers/atomics) alone
#define FENCE_BAR() do { \
    asm volatile("s_waitcnt lgkmcnt(0)" ::: "memory"); \
    __builtin_amdgcn_sched_barrier(0); \
    __builtin_amdgcn_s_barrier(); \
    __builtin_amdgcn_sched_barrier(0); \
} while (0)

// ---------------- CSR build: histogram of dst ----------------
__global__ __launch_bounds__(256) void egnn_hist(
    const int* __restrict__ dst, int* __restrict__ hc)
{
    int e = blockIdx.x * 256 + threadIdx.x;
    if (e < NE) atomicAdd(&hc[dst[e]], 1);
}

// ---------------- CSR build: exclusive scan (1 block, 1024 thr) ----------------
__global__ __launch_bounds__(1024) void egnn_scan(
    int* __restrict__ hc, int* __restrict__ rowptr)
{
    __shared__ int part[1024];
    const int t = threadIdx.x;
    const int C = (NN + 1023) / 1024;   // 49
    const int b0 = t * C;
    int s = 0;
    for (int i = 0; i < C; ++i) {
        int idx = b0 + i;
        if (idx < NN) s += hc[idx];
    }
    part[t] = s;
    __syncthreads();
    for (int off = 1; off < 1024; off <<= 1) {
        int v = (t >= off) ? part[t - off] : 0;
        __syncthreads();
        part[t] += v;
        __syncthreads();
    }
    int run = part[t] - s;              // exclusive base for this chunk
    for (int i = 0; i < C; ++i) {
        int idx = b0 + i;
        if (idx < NN) {
            int v = hc[idx];
            rowptr[idx] = run;
            hc[idx] = run;              // cursor init
            run += v;
        }
    }
    if (t == 1023) rowptr[NN] = part[1023];
}

// ---------------- CSR build: permute edges into dst-sorted order ----------------
__global__ __launch_bounds__(256) void egnn_scatter(
    const int* __restrict__ src, const int* __restrict__ dst,
    const float* __restrict__ pos, int* __restrict__ cursor,
    int* __restrict__ eSrc, int* __restrict__ eDst, float* __restrict__ eD2)
{
    int e = blockIdx.x * 256 + threadIdx.x;
    if (e >= NE) return;
    int s = src[e], d = dst[e];
    float rx = pos[3*d+0] - pos[3*s+0];
    float ry = pos[3*d+1] - pos[3*s+1];
    float rz = pos[3*d+2] - pos[3*s+2];
    int p = atomicAdd(&cursor[d], 1);
    eSrc[p] = s;
    eDst[p] = d;
    eD2[p]  = rx*rx + ry*ry + rz*rz;
}

// ---------------- weight prep: transpose + bf16-convert edge + pos weights --------
__global__ __launch_bounds__(256) void egnn_prep_w(
    const float* __restrict__ We1, const float* __restrict__ We2,
    const float* __restrict__ Wp1,
    unsigned short* __restrict__ Wg1, unsigned short* __restrict__ Wg2,
    unsigned short* __restrict__ Wgp1)
{
    int i = blockIdx.x * 256 + threadIdx.x;
    if (i < 4 * 64 * 128) {
        int k = i & 127, n = (i >> 7) & 63, l = i >> 13;
        Wg1[(size_t)(l * 64 + n) * 136 + k] = f2bf(We1[((size_t)l * 129 + k) * 64 + n]);
    }
    if (i < 4 * 64 * 64) {
        int h = i & 63, n = (i >> 6) & 63, l = i >> 12;
        Wg2[(size_t)(l * 64 + n) * 72 + h]  = f2bf(We2[((size_t)l * 64 + h) * 64 + n]);
        Wgp1[(size_t)(l * 64 + n) * 72 + h] = f2bf(Wp1[((size_t)l * 64 + h) * 64 + n]);
    }
}

// ---------------- weight prep: node weights ----------------
__global__ __launch_bounds__(256) void egnn_prep_wn(
    const float* __restrict__ Wn1, const float* __restrict__ Wn2,
    unsigned short* __restrict__ Wgn1, unsigned short* __restrict__ Wgn2)
{
    int i = blockIdx.x * 256 + threadIdx.x;
    if (i < 4 * 64 * 128) {
        int k = i & 127, n = (i >> 7) & 63, l = i >> 13;
        Wgn1[(size_t)(l * 64 + n) * 136 + k] = f2bf(Wn1[((size_t)l * 128 + k) * 64 + n]);
    }
    if (i < 4 * 64 * 64) {
        int h = i & 63, n = (i >> 6) & 63, l = i >> 12;
        Wgn2[(size_t)(l * 64 + n) * 72 + h] = f2bf(Wn2[((size_t)l * 64 + h) * 64 + n]);
    }
}

// ---------------- x0 -> bf16 ----------------
__global__ __launch_bounds__(256) void egnn_xbf(
    const float* __restrict__ x, unsigned short* __restrict__ xbf)
{
    int i = blockIdx.x * 256 + threadIdx.x;   // one float4 per thread
    if (i >= NN * 16) return;
    float4 v = ((const float4*)x)[i];
    ((uint2*)xbf)[i] = make_uint2(pk2(v.x, v.y), pk2(v.z, v.w));
}

// ---------------- edge MLP: multi-tile pipelined, counted-vmcnt, bf16 MFMA --------
// 4 waves: eh=w>>1 (32-edge half), ch=w&1 (32-ch half). Double-buffered xls.
// ALL per-iteration vmem ops have STATIC counts so the bottom-of-iter wait can be a
// counted vmcnt (gather retired; atomics float):
//   per iter after gather(4): nid refill 4 + d2 2 [+ posidx 2 + posatom 3] + agg atomics 16
//   -> non-POS: vmcnt(22), POS: vmcnt(27). Prologue: vmcnt(6)/(8).
template<bool POS>
__global__ __launch_bounds__(256) void egnn_edge(
    const unsigned short* __restrict__ xbf, const float* __restrict__ eD2,
    const int* __restrict__ eSrc, const int* __restrict__ eDst,
    const float* __restrict__ pos,
    const unsigned short* __restrict__ Wg1, const unsigned short* __restrict__ Wg2,
    const unsigned short* __restrict__ Wgp1,
    const float* __restrict__ We1,   // fp32, d2 row (row 128)
    const float* __restrict__ be1, const float* __restrict__ be2,
    const float* __restrict__ bp1, const float* __restrict__ Wp2,
    const float* __restrict__ bp2,
    float* __restrict__ agg, float* __restrict__ dpos, int layer)
{
    // [xls0 16384][xls1 16384][m1l 9216][m2s 9216]
    __shared__ __align__(16) unsigned char pool[16384 * 2 + 9216 * 2];
    unsigned short* const xls0 = (unsigned short*)pool;
    unsigned short* const xls1 = (unsigned short*)(pool + 16384);
    unsigned short* const m1l  = (unsigned short*)(pool + 32768);
    unsigned short* const m2s  = (unsigned short*)(pool + 41984);

    const int t    = threadIdx.x;
    const int lane = t & 63;
    const int w    = t >> 6;
    const int l15  = lane & 15;
    const int g    = lane >> 4;
    const int g4   = g * 4;
    const int eh   = w >> 1;
    const int ch   = w & 1;
    const int er   = lane >> 4;          // gather: row within 4-row group
    const int half = (lane >> 3) & 1;    // gather: 0=dst-half, 1=src-half
    const int c    = lane & 7;           // gather: 16B chunk within half
    const int tile0 = blockIdx.x * TPB;
    const int wofs16 = __builtin_amdgcn_readfirstlane(w * 16);

    // ---- hoist loop-invariant weight fragments ----
    const unsigned short* W1b = &Wg1[(size_t)(layer * 64) * 136];
    const unsigned short* W2b = &Wg2[(size_t)(layer * 64) * 72];
    short8 w1f0[4], w1f1[4], w2f0[2], w2f1[2];
    #pragma unroll
    for (int ks = 0; ks < 4; ++ks) {
        w1f0[ks] = *(const short8*)&W1b[(ch * 32 +      l15) * 136 + ks * 32 + g * 8];
        w1f1[ks] = *(const short8*)&W1b[(ch * 32 + 16 + l15) * 136 + ks * 32 + g * 8];
    }
    #pragma unroll
    for (int ks = 0; ks < 2; ++ks) {
        w2f0[ks] = *(const short8*)&W2b[(ch * 32 +      l15) * 72 + ks * 32 + g * 8];
        w2f1[ks] = *(const short8*)&W2b[(ch * 32 + 16 + l15) * 72 + ks * 32 + g * 8];
    }
    float4 wrv[2], b1v[2], b2v[2];
    {
        const float* Wr = &We1[((size_t)layer * 129 + 128) * 64];
        const float* B1 = &be1[layer * 64];
        const float* B2 = &be2[layer * 64];
        #pragma unroll
        for (int nt = 0; nt < 2; ++nt) {
            int n0 = ch * 32 + nt * 16 + g * 4;
            wrv[nt] = *(const float4*)&Wr[n0];
            b1v[nt] = *(const float4*)&B1[n0];
            b2v[nt] = *(const float4*)&B2[n0];
        }
    }
    // pos-head constants
    float4 b1p[4], w2p[4];
    float bp2v = 0.f;
    if (POS) {
        #pragma unroll
        for (int m = 0; m < 4; ++m) {
            b1p[m] = *(const float4*)&bp1[(size_t)layer * 64 + m * 16 + g4];
            w2p[m] = *(const float4*)&Wp2[(size_t)layer * 64 + m * 16 + g4];
        }
        bp2v = bp2[layer];
    }

    const int* const ip = half ? eSrc : eDst;
    const int ebase = w * 16 + er;       // + i*4 ; (ebase+i*4)&7 == row&7

    // ---- prologue ----
    int nid[4];
    {
        const int gb0 = tile0 * 64;
        #pragma unroll
        for (int i = 0; i < 4; ++i) nid[i] = ip[gb0 + ebase + i * 4];
        #pragma unroll
        for (int i = 0; i < 4; ++i)
            gload_lds16(&xbf[(size_t)nid[i] * 64 + ((c ^ ((ebase + i * 4) & 7)) << 3)],
                        xls0 + w * 2048 + i * 512);
        __builtin_amdgcn_sched_barrier(0);
        // after-gather ops: nid refill 4 + d2 2 (+ posidx 2)
        #pragma unroll
        for (int i = 0; i < 4; ++i) nid[i] = ip[gb0 + 64 + ebase + i * 4];
    }
    float d2c0 = eD2[tile0 * 64 + eh * 32 + l15];
    float d2c1 = eD2[tile0 * 64 + eh * 32 + 16 + l15];
    int pD = 0, pS = 0;
    if (POS) {
        pD = eDst[tile0 * 64 + wofs16 + l15];
        pS = eSrc[tile0 * 64 + wofs16 + l15];
    }
    __builtin_amdgcn_sched_barrier(0);
    if (POS) asm volatile("s_waitcnt vmcnt(8)" ::: "memory");
    else     asm volatile("s_waitcnt vmcnt(6)" ::: "memory");
    __builtin_amdgcn_sched_barrier(0);
    __builtin_amdgcn_s_barrier();
    __builtin_amdgcn_sched_barrier(0);

    const f32x4 zero = {0.f, 0.f, 0.f, 0.f};

    for (int tt = 0; tt < TPB; ++tt) {
        const int b = tt & 1;
        unsigned short* const xcur = b ? xls1 : xls0;
        unsigned short* const xnxt = b ? xls0 : xls1;
        const int gb = (tile0 + tt) * 64;

        float d2n0 = 0.f, d2n1 = 0.f;
        int pDn = 0, pSn = 0;
        if (tt + 1 < TPB) {
            const int gb1 = gb + 64;
            #pragma unroll
            for (int i = 0; i < 4; ++i)
                gload_lds16(&xbf[(size_t)nid[i] * 64 + ((c ^ ((ebase + i * 4) & 7)) << 3)],
                            xnxt + w * 2048 + i * 512);
            __builtin_amdgcn_sched_barrier(0);
            // static after-gather group: d2 2 (+posidx 2) + nid refill 4 (may read
            // past eDst end on the last tiles -> lands in adjacent ws buffers, unused)
            d2n0 = eD2[gb1 + eh * 32 + l15];
            d2n1 = eD2[gb1 + eh * 32 + 16 + l15];
            if (POS) {
                pDn = eDst[gb1 + wofs16 + l15];
                pSn = eSrc[gb1 + wofs16 + l15];
            }
            const int gb2 = gb + 128;
            #pragma unroll
            for (int i = 0; i < 4; ++i) nid[i] = ip[gb2 + ebase + i * 4];
        }

        // GEMM1: D^T[n][e], K=128
        f32x4 a00 = zero, a01 = zero, a10 = zero, a11 = zero;
        {
            const int r0 = (eh * 32 + l15) * 128;
            const int r1 = r0 + 16 * 128;
            const int r7 = l15 & 7;
            #pragma unroll
            for (int ks = 0; ks < 4; ++ks) {
                int col = (((ks << 2) + g) ^ r7) << 3;
                short8 fb0 = *(const short8*)&xcur[r0 + col];
                short8 fb1 = *(const short8*)&xcur[r1 + col];
                a00 = __builtin_amdgcn_mfma_f32_16x16x32_bf16(w1f0[ks], fb0, a00, 0, 0, 0);
                a01 = __builtin_amdgcn_mfma_f32_16x16x32_bf16(w1f0[ks], fb1, a01, 0, 0, 0);
                a10 = __builtin_amdgcn_mfma_f32_16x16x32_bf16(w1f1[ks], fb0, a10, 0, 0, 0);
                a11 = __builtin_amdgcn_mfma_f32_16x16x32_bf16(w1f1[ks], fb1, a11, 0, 0, 0);
            }
        }
        // ep1: + d2 row + bias, SiLU, quantize -> m1l
        {
            int e0 = eh * 32 + l15;
            int e1 = e0 + 16;
            #pragma unroll
            for (int nt = 0; nt < 2; ++nt) {
                int n0 = ch * 32 + nt * 16 + g * 4;
                float4 wr = wrv[nt], bb = b1v[nt];
                f32x4 acc0 = nt ? a10 : a00;
                f32x4 acc1 = nt ? a11 : a01;
                float r0 = silu_f(acc0.x + d2c0 * wr.x + bb.x);
                float r1 = silu_f(acc0.y + d2c0 * wr.y + bb.y);
                float r2 = silu_f(acc0.z + d2c0 * wr.z + bb.z);
                float r3 = silu_f(acc0.w + d2c0 * wr.w + bb.w);
                *(uint2*)&m1l[e0 * 72 + n0] = make_uint2(pk2(r0, r1), pk2(r2, r3));
                r0 = silu_f(acc1.x + d2c1 * wr.x + bb.x);
                r1 = silu_f(acc1.y + d2c1 * wr.y + bb.y);
                r2 = silu_f(acc1.z + d2c1 * wr.z + bb.z);
                r3 = silu_f(acc1.w + d2c1 * wr.w + bb.w);
                *(uint2*)&m1l[e1 * 72 + n0] = make_uint2(pk2(r0, r1), pk2(r2, r3));
            }
        }
        FENCE_BAR();   // (E): m1l written

        // GEMM2: K=64
        f32x4 c00 = zero, c01 = zero, c10 = zero, c11 = zero;
        #pragma unroll
        for (int ks = 0; ks < 2; ++ks) {
            short8 fb0 = *(const short8*)&m1l[(eh * 32 +      l15) * 72 + ks * 32 + g * 8];
            short8 fb1 = *(const short8*)&m1l[(eh * 32 + 16 + l15) * 72 + ks * 32 + g * 8];
            c00 = __builtin_amdgcn_mfma_f32_16x16x32_bf16(w2f0[ks], fb0, c00, 0, 0, 0);
            c01 = __builtin_amdgcn_mfma_f32_16x16x32_bf16(w2f0[ks], fb1, c01, 0, 0, 0);
            c10 = __builtin_amdgcn_mfma_f32_16x16x32_bf16(w2f1[ks], fb0, c10, 0, 0, 0);
            c11 = __builtin_amdgcn_mfma_f32_16x16x32_bf16(w2f1[ks], fb1, c11, 0, 0, 0);
        }

        // ep2: + bias, SiLU -> m2s (bf16, separate buffer; no overlay barrier needed)
        {
            int e0 = eh * 32 + l15;
            int e1 = e0 + 16;
            #pragma unroll
            for (int nt = 0; nt < 2; ++nt) {
                int n0 = ch * 32 + nt * 16 + g * 4;
                float4 bb = b2v[nt];
                f32x4 acc0 = nt ? c10 : c00;
                f32x4 acc1 = nt ? c11 : c01;
                float r0 = silu_f(acc0.x + bb.x);
                float r1 = silu_f(acc0.y + bb.y);
                float r2 = silu_f(acc0.z + bb.z);
                float r3 = silu_f(acc0.w + bb.w);
                *(uint2*)&m2s[e0 * 72 + n0] = make_uint2(pk2(r0, r1), pk2(r2, r3));
                r0 = silu_f(acc1.x + bb.x);
                r1 = silu_f(acc1.y + bb.y);
                r2 = silu_f(acc1.z + bb.z);
                r3 = silu_f(acc1.w + bb.w);
                *(uint2*)&m2s[e1 * 72 + n0] = make_uint2(pk2(r0, r1), pk2(r2, r3));
            }
        }
        FENCE_BAR();   // (G): m2s visible to all waves

        if (POS) {
            // per-wave MFMA pos head over this wave's 16 edges
            f32x4 pa[4] = {zero, zero, zero, zero};
            const unsigned short* WPb = &Wgp1[(size_t)(layer * 64) * 72];
            #pragma unroll
            for (int ks = 0; ks < 2; ++ks) {
                short8 fb = *(const short8*)&m2s[(w * 16 + l15) * 72 + ks * 32 + g * 8];
                #pragma unroll
                for (int m = 0; m < 4; ++m) {
                    short8 wf = *(const short8*)&WPb[(size_t)(m * 16 + l15) * 72 + ks * 32 + g * 8];
                    pa[m] = __builtin_amdgcn_mfma_f32_16x16x32_bf16(wf, fb, pa[m], 0, 0, 0);
                }
            }
            float part = 0.0f;
            #pragma unroll
            for (int m = 0; m < 4; ++m) {
                part += silu_f(pa[m].x + b1p[m].x) * w2p[m].x;
                part += silu_f(pa[m].y + b1p[m].y) * w2p[m].y;
                part += silu_f(pa[m].z + b1p[m].z) * w2p[m].z;
                part += silu_f(pa[m].w + b1p[m].w) * w2p[m].w;
            }
            part += __shfl_xor(part, 16);
            part += __shfl_xor(part, 32);
            if (lane < 16) {
                float cv = part + bp2v;
                int d = pD, s = pS;
                float rx = pos[3*(size_t)d+0] - pos[3*(size_t)s+0];
                float ry = pos[3*(size_t)d+1] - pos[3*(size_t)s+1];
                float rz = pos[3*(size_t)d+2] - pos[3*(size_t)s+2];
                atomicAdd(&dpos[3*(size_t)d+0], rx * cv);
                atomicAdd(&dpos[3*(size_t)d+1], ry * cv);
                atomicAdd(&dpos[3*(size_t)d+2], rz * cv);
            }
        }

        // scatter: wave w owns edges [w*16, +16), lane = channel.
        // dst indices via wave-uniform scalar loads; EXACTLY 16 atomics (0-padded runs)
        {
            int dd[16];
            #pragma unroll
            for (int i = 0; i < 16; ++i) dd[i] = eDst[gb + wofs16 + i];
            float v[16];
            #pragma unroll
            for (int i = 0; i < 16; ++i) v[i] = bf2f(m2s[(w * 16 + i) * 72 + lane]);
            float run = 0.0f;
            #pragma unroll
            for (int i = 0; i < 16; ++i) {
                run += v[i];
                bool bi = (i == 15) || (dd[i + 1] != dd[i]);
                float ai = bi ? run : 0.0f;
                atomicAdd(&agg[(size_t)dd[i] * 64 + lane], ai);
                run = bi ? 0.0f : run;
            }
        }

        if (tt + 1 < TPB) {
            d2c0 = d2n0; d2c1 = d2n1;
            if (POS) { pD = pDn; pS = pSn; }
            // counted wait: gather(t+1) retired; atomics keep floating.
            __builtin_amdgcn_sched_barrier(0);
            if (POS) asm volatile("s_waitcnt vmcnt(27)" ::: "memory");
            else     asm volatile("s_waitcnt vmcnt(22)" ::: "memory");
            __builtin_amdgcn_sched_barrier(0);
            asm volatile("s_waitcnt lgkmcnt(0)" ::: "memory");
            __builtin_amdgcn_sched_barrier(0);
            __builtin_amdgcn_s_barrier();
            __builtin_amdgcn_sched_barrier(0);
        }
    }
}

// ---------------- node MLP via bf16 MFMA (R8-proven) ----------------
template<bool WRITE_F32>
__global__ __launch_bounds__(256) void egnn_node_mfma(
    const unsigned short* __restrict__ xbf, const float* __restrict__ agg,
    const unsigned short* __restrict__ Wgn1, const unsigned short* __restrict__ Wgn2,
    const float* __restrict__ bn1, const float* __restrict__ bn2,
    float* __restrict__ xout, unsigned short* __restrict__ xbf_out, int layer)
{
    __shared__ __align__(16) unsigned char pool[16384 + 9216];
    unsigned short* const xpl = (unsigned short*)pool;
    unsigned short* const m1l = (unsigned short*)(pool + 16384);
    float* const          sXf = (float*)pool;

    const int t    = threadIdx.x;
    const int lane = t & 63;
    const int w    = t >> 6;
    const int l15  = lane & 15;
    const int g    = lane >> 4;
    const int eh   = w >> 1;
    const int ch   = w & 1;
    const int base = blockIdx.x * 64;
    const int nval = (NN - base < 64) ? (NN - base) : 64;

    // stage x-half via gload_lds (linear rows, source chunk-swizzled)
    #pragma unroll
    for (int i = 0; i < 2; ++i) {
        int e = w * 16 + i * 8 + (lane >> 3);
        int node = base + ((e < nval) ? e : 0);
        gload_lds16(&xbf[(size_t)node * 64 + (((lane & 7) ^ (e & 7)) << 3)],
                    xpl + w * 1024 + i * 512);
    }
    __builtin_amdgcn_sched_barrier(0);

    const unsigned short* W1b = &Wgn1[(size_t)(layer * 64) * 136];
    const unsigned short* W2b = &Wgn2[(size_t)(layer * 64) * 72];
    short8 w1f0[4], w1f1[4], w2f0[2], w2f1[2];
    #pragma unroll
    for (int ks = 0; ks < 4; ++ks) {
        w1f0[ks] = *(const short8*)&W1b[(ch * 32 +      l15) * 136 + ks * 32 + g * 8];
        w1f1[ks] = *(const short8*)&W1b[(ch * 32 + 16 + l15) * 136 + ks * 32 + g * 8];
    }
    #pragma unroll
    for (int ks = 0; ks < 2; ++ks) {
        w2f0[ks] = *(const short8*)&W2b[(ch * 32 +      l15) * 72 + ks * 32 + g * 8];
        w2f1[ks] = *(const short8*)&W2b[(ch * 32 + 16 + l15) * 72 + ks * 32 + g * 8];
    }
    float4 b1v[2], b2v[2];
    {
        const float* B1 = &bn1[layer * 64];
        const float* B2 = &bn2[layer * 64];
        #pragma unroll
        for (int nt = 0; nt < 2; ++nt) {
            int n0 = ch * 32 + nt * 16 + g * 4;
            b1v[nt] = *(const float4*)&B1[n0];
            b2v[nt] = *(const float4*)&B2[n0];
        }
    }

    // stage agg-half: fp32 read + pk2 -> plane1 (swizzled ds_write)
    {
        int e = t >> 2, q = t & 3;
        int node = base + ((e < nval) ? e : 0);
        const float4* ap = (const float4*)&agg[(size_t)node * 64 + q * 16];
        float4 v0 = ap[0], v1 = ap[1], v2 = ap[2], v3 = ap[3];
        uint4 u0, u1;
        u0.x = pk2(v0.x, v0.y); u0.y = pk2(v0.z, v0.w);
        u0.z = pk2(v1.x, v1.y); u0.w = pk2(v1.z, v1.w);
        u1.x = pk2(v2.x, v2.y); u1.y = pk2(v2.z, v2.w);
        u1.z = pk2(v3.x, v3.y); u1.w = pk2(v3.z, v3.w);
        *(uint4*)&xpl[4096 + e * 64 + (((2 * q)     ^ (e & 7)) << 3)] = u0;
        *(uint4*)&xpl[4096 + e * 64 + (((2 * q + 1) ^ (e & 7)) << 3)] = u1;
    }
    __syncthreads();   // full drain: gloads + ds_writes

    const f32x4 zero = {0.f, 0.f, 0.f, 0.f};
    f32x4 a00 = zero, a01 = zero, a10 = zero, a11 = zero;
    {
        const int e0 = eh * 32 + l15;
        const int e1 = e0 + 16;
        const int r7 = e0 & 7;
        #pragma unroll
        for (int ks = 0; ks < 4; ++ks) {
            int kc = (ks << 2) + g;
            int off0 = (kc >> 3) * 4096 + e0 * 64 + (((kc & 7) ^ r7) << 3);
            int off1 = (kc >> 3) * 4096 + e1 * 64 + (((kc & 7) ^ r7) << 3);
            short8 fb0 = *(const short8*)&xpl[off0];
            short8 fb1 = *(const short8*)&xpl[off1];
            a00 = __builtin_amdgcn_mfma_f32_16x16x32_bf16(w1f0[ks], fb0, a00, 0, 0, 0);
            a01 = __builtin_amdgcn_mfma_f32_16x16x32_bf16(w1f0[ks], fb1, a01, 0, 0, 0);
            a10 = __builtin_amdgcn_mfma_f32_16x16x32_bf16(w1f1[ks], fb0, a10, 0, 0, 0);
            a11 = __builtin_amdgcn_mfma_f32_16x16x32_bf16(w1f1[ks], fb1, a11, 0, 0, 0);
        }
    }
    {
        int e0 = eh * 32 + l15;
        int e1 = e0 + 16;
        #pragma unroll
        for (int nt = 0; nt < 2; ++nt) {
            int n0 = ch * 32 + nt * 16 + g * 4;
            float4 bb = b1v[nt];
            f32x4 acc0 = nt ? a10 : a00;
            f32x4 acc1 = nt ? a11 : a01;
            float r0 = silu_f(acc0.x + bb.x);
            float r1 = silu_f(acc0.y + bb.y);
            float r2 = silu_f(acc0.z + bb.z);
            float r3 = silu_f(acc0.w + bb.w);
            *(uint2*)&m1l[e0 * 72 + n0] = make_uint2(pk2(r0, r1), pk2(r2, r3));
            r0 = silu_f(acc1.x + bb.x);
            r1 = silu_f(acc1.y + bb.y);
            r2 = silu_f(acc1.z + bb.z);
            r3 = silu_f(acc1.w + bb.w);
            *(uint2*)&m1l[e1 * 72 + n0] = make_uint2(pk2(r0, r1), pk2(r2, r3));
        }
    }
    __syncthreads();

    f32x4 c00 = zero, c01 = zero, c10 = zero, c11 = zero;
    #pragma unroll
    for (int ks = 0; ks < 2; ++ks) {
        short8 fb0 = *(const short8*)&m1l[(eh * 32 +      l15) * 72 + ks * 32 + g * 8];
        short8 fb1 = *(const short8*)&m1l[(eh * 32 + 16 + l15) * 72 + ks * 32 + g * 8];
        c00 = __builtin_amdgcn_mfma_f32_16x16x32_bf16(w2f0[ks], fb0, c00, 0, 0, 0);
        c01 = __builtin_amdgcn_mfma_f32_16x16x32_bf16(w2f0[ks], fb1, c01, 0, 0, 0);
        c10 = __builtin_amdgcn_mfma_f32_16x16x32_bf16(w2f1[ks], fb0, c10, 0, 0, 0);
        c11 = __builtin_amdgcn_mfma_f32_16x16x32_bf16(w2f1[ks], fb1, c11, 0, 0, 0);
    }
    __syncthreads();   // m1l readers done -> sXf overlay safe

    {
        int e0 = eh * 32 + l15;
        int e1 = e0 + 16;
        #pragma unroll
        for (int nt = 0; nt < 2; ++nt) {
            int n0 = ch * 32 + nt * 16 + g * 4;
            float4 bb = b2v[nt];
            f32x4 acc0 = nt ? c10 : c00;
            f32x4 acc1 = nt ? c11 : c01;
            sXf[e0 * 65 + n0 + 0] = acc0.x + bb.x;
            sXf[e0 * 65 + n0 + 1] = acc0.y + bb.y;
            sXf[e0 * 65 + n0 + 2] = acc0.z + bb.z;
            sXf[e0 * 65 + n0 + 3] = acc0.w + bb.w;
            sXf[e1 * 65 + n0 + 0] = acc1.x + bb.x;
            sXf[e1 * 65 + n0 + 1] = acc1.y + bb.y;
            sXf[e1 * 65 + n0 + 2] = acc1.z + bb.z;
            sXf[e1 * 65 + n0 + 3] = acc1.w + bb.w;
        }
    }
    __syncthreads();

    if (WRITE_F32) {
        #pragma unroll
        for (int i = 0; i < 4; ++i) {
            int idx = i * 256 + t;
            int e = idx >> 4, c = idx & 15;
            if (e < nval) {
                float4 v;
                const float* p = &sXf[e * 65 + c * 4];
                v.x = p[0]; v.y = p[1]; v.z = p[2]; v.w = p[3];
                *reinterpret_cast<float4*>(&xout[(size_t)(base + e) * 64 + c * 4]) = v;
            }
        }
    }
    {
        int e = t >> 2, q = t & 3;
        if (e < nval) {
            const float* p = &sXf[e * 65 + q * 16];
            uint4 u0, u1;
            u0.x = pk2(p[0],  p[1]);  u0.y = pk2(p[2],  p[3]);
            u0.z = pk2(p[4],  p[5]);  u0.w = pk2(p[6],  p[7]);
            u1.x = pk2(p[8],  p[9]);  u1.y = pk2(p[10], p[11]);
            u1.z = pk2(p[12], p[13]); u1.w = pk2(p[14], p[15]);
            *(uint4*)&xbf_out[(size_t)(base + e) * 64 + q * 16 + 0] = u0;
            *(uint4*)&xbf_out[(size_t)(base + e) * 64 + q * 16 + 8] = u1;
        }
    }
}

// ---------------- finalize positions ----------------
__global__ __launch_bounds__(256) void egnn_final(
    const float* __restrict__ pos, const float* __restrict__ dpos,
    const int* __restrict__ rowptr, const float* __restrict__ logit,
    float* __restrict__ pos_out)
{
    int i = blockIdx.x * 256 + threadIdx.x;
    if (i >= NN * 3) return;
    int node = i / 3;
    float dg = fmaxf((float)(rowptr[node + 1] - rowptr[node]), 1.0f);
    float sig = 1.0f / (1.0f + __expf(-logit[0]));
    float upd = (dpos[i] / dg) * sig;
    upd = fminf(fmaxf(upd, -5.0f), 5.0f);
    float p = pos[i] + upd;
    pos_out[i] = fminf(fmaxf(p, -500.0f), 500.0f);
}

extern "C" void kernel_launch(void* const* d_in, const int* in_sizes, int n_in,
                              void* d_out, int out_size, void* d_ws, size_t ws_size,
                              hipStream_t stream)
{
    const float* x0    = (const float*)d_in[0];
    const float* pos   = (const float*)d_in[1];
    const int*   src   = (const int*)d_in[2];
    const int*   dst   = src + NE;
    const float* We1   = (const float*)d_in[3];
    const float* be1   = (const float*)d_in[4];
    const float* We2   = (const float*)d_in[5];
    const float* be2   = (const float*)d_in[6];
    const float* Wn1   = (const float*)d_in[7];
    const float* bn1   = (const float*)d_in[8];
    const float* Wn2   = (const float*)d_in[9];
    const float* bn2   = (const float*)d_in[10];
    const float* Wp1   = (const float*)d_in[11];
    const float* bp1   = (const float*)d_in[12];
    const float* Wp2   = (const float*)d_in[13];
    const float* bp2   = (const float*)d_in[14];
    const float* logit = (const float*)d_in[15];

    float* xout    = (float*)d_out;                 // [NN,64]
    float* pos_out = xout + (size_t)NN * 64;        // [NN,3]

    float* ws  = (float*)d_ws;
    float* agg  = ws;  ws += (size_t)NN * 64;
    float* dpos = ws;  ws += (size_t)NN * 3;
    float* eD2  = ws;  ws += NE;
    int* rowptr = (int*)ws;  ws += NN + 1;
    int* hc     = (int*)ws;  ws += NN;              // hist -> cursor
    int* eSrc   = (int*)ws;  ws += NE;
    int* eDst   = (int*)ws;  ws += NE;
    unsigned short* xbf = (unsigned short*)ws;      // [NN,64] bf16
    ws += (size_t)NN * 32;
    unsigned short* Wg1  = (unsigned short*)ws;     // 4*64*136
    unsigned short* Wg2  = Wg1 + 4 * 64 * 136;      // 4*64*72
    unsigned short* Wgn1 = Wg2 + 4 * 64 * 72;       // 4*64*136
    unsigned short* Wgn2 = Wgn1 + 4 * 64 * 136;     // 4*64*72
    unsigned short* Wgp1 = Wgn2 + 4 * 64 * 72;      // 4*64*72

    hipMemsetAsync(hc, 0, NN * sizeof(int), stream);
    hipMemsetAsync(dpos, 0, (size_t)NN * 3 * sizeof(float), stream);
    egnn_hist<<<NE / 256, 256, 0, stream>>>(dst, hc);
    egnn_scan<<<1, 1024, 0, stream>>>(hc, rowptr);
    egnn_scatter<<<NE / 256, 256, 0, stream>>>(src, dst, pos, hc, eSrc, eDst, eD2);
    egnn_prep_w<<<128, 256, 0, stream>>>(We1, We2, Wp1, Wg1, Wg2, Wgp1);
    egnn_prep_wn<<<128, 256, 0, stream>>>(Wn1, Wn2, Wgn1, Wgn2);
    egnn_xbf<<<(NN * 16 + 255) / 256, 256, 0, stream>>>(x0, xbf);

    const int nblk = NTILES / TPB;                  // 1250
    const int nodeblk = (NN + 63) / 64;             // 782
    for (int l = 0; l < 4; ++l) {
        hipMemsetAsync(agg, 0, (size_t)NN * 64 * sizeof(float), stream);
        if (l == 3) {
            egnn_edge<true><<<nblk, 256, 0, stream>>>(
                xbf, eD2, eSrc, eDst, pos, Wg1, Wg2, Wgp1, We1, be1, be2,
                bp1, Wp2, bp2, agg, dpos, l);
            egnn_node_mfma<true><<<nodeblk, 256, 0, stream>>>(
                xbf, agg, Wgn1, Wgn2, bn1, bn2, xout, xbf, l);
        } else {
            egnn_edge<false><<<nblk, 256, 0, stream>>>(
                xbf, eD2, eSrc, eDst, pos, Wg1, Wg2, Wgp1, We1, be1, be2,
                bp1, Wp2, bp2, agg, dpos, l);
            egnn_node_mfma<false><<<nodeblk, 256, 0, stream>>>(
                xbf, agg, Wgn1, Wgn2, bn1, bn2, xout, xbf, l);
        }
    }
    egnn_final<<<(NN * 3 + 255) / 256, 256, 0, stream>>>(pos, dpos, rowptr, logit, pos_out);
}

// Round 13
// 877.893 us; speedup vs baseline: 1.5805x; 1.5805x over previous
//
#include <hip/hip_runtime.h>

#define NN 50000
#define NE 800000
#define NTILES 12500
#define TPB 10   // tiles (of 64 edges) per block; 12500 % 10 == 0 -> grid 1250

typedef __attribute__((ext_vector_type(8))) short short8;
typedef __attribute__((ext_vector_type(4))) float f32x4;

__device__ __forceinline__ float silu_f(float v) {
    return v / (1.0f + __expf(-v));
}
__device__ __forceinline__ unsigned short f2bf(float f) {
    unsigned u = __float_as_uint(f);
    u += 0x7fffu + ((u >> 16) & 1u);        // round-to-nearest-even
    return (unsigned short)(u >> 16);
}
__device__ __forceinline__ unsigned pk2(float a, float b) {
    return (unsigned)f2bf(a) | ((unsigned)f2bf(b) << 16);
}
__device__ __forceinline__ float bf2f(unsigned short v) {
    return __uint_as_float((unsigned)v << 16);
}
__device__ __forceinline__ float ulo(unsigned u) { return __uint_as_float(u << 16); }
__device__ __forceinline__ float uhi(unsigned u) { return __uint_as_float(u & 0xffff0000u); }
__device__ __forceinline__ void gload_lds16(const unsigned short* g, unsigned short* l) {
    __builtin_amdgcn_global_load_lds(
        (const __attribute__((address_space(1))) unsigned int*)g,
        (__attribute__((address_space(3))) unsigned int*)l, 16, 0, 0);
}
#define SB() __builtin_amdgcn_sched_barrier(0)

// ---------------- CSR build: histogram of dst ----------------
__global__ __launch_bounds__(256) void egnn_hist(
    const int* __restrict__ dst, int* __restrict__ hc)
{
    int e = blockIdx.x * 256 + threadIdx.x;
    if (e < NE) atomicAdd(&hc[dst[e]], 1);
}

// ---------------- CSR build: exclusive scan (1 block, 1024 thr) ----------------
__global__ __launch_bounds__(1024) void egnn_scan(
    int* __restrict__ hc, int* __restrict__ rowptr)
{
    __shared__ int part[1024];
    const int t = threadIdx.x;
    const int C = (NN + 1023) / 1024;   // 49
    const int b0 = t * C;
    int s = 0;
    for (int i = 0; i < C; ++i) {
        int idx = b0 + i;
        if (idx < NN) s += hc[idx];
    }
    part[t] = s;
    __syncthreads();
    for (int off = 1; off < 1024; off <<= 1) {
        int v = (t >= off) ? part[t - off] : 0;
        __syncthreads();
        part[t] += v;
        __syncthreads();
    }
    int run = part[t] - s;              // exclusive base for this chunk
    for (int i = 0; i < C; ++i) {
        int idx = b0 + i;
        if (idx < NN) {
            int v = hc[idx];
            rowptr[idx] = run;
            hc[idx] = run;              // cursor init
            run += v;
        }
    }
    if (t == 1023) rowptr[NN] = part[1023];
}

// ---------------- CSR build: permute edges into dst-sorted order ----------------
__global__ __launch_bounds__(256) void egnn_scatter(
    const int* __restrict__ src, const int* __restrict__ dst,
    const float* __restrict__ pos, int* __restrict__ cursor,
    int* __restrict__ eSrc, int* __restrict__ eDst, float* __restrict__ eD2)
{
    int e = blockIdx.x * 256 + threadIdx.x;
    if (e >= NE) return;
    int s = src[e], d = dst[e];
    float rx = pos[3*d+0] - pos[3*s+0];
    float ry = pos[3*d+1] - pos[3*s+1];
    float rz = pos[3*d+2] - pos[3*s+2];
    int p = atomicAdd(&cursor[d], 1);
    eSrc[p] = s;
    eDst[p] = d;
    eD2[p]  = rx*rx + ry*ry + rz*rz;
}

// ---------------- weight prep: transpose + bf16-convert edge + pos weights --------
__global__ __launch_bounds__(256) void egnn_prep_w(
    const float* __restrict__ We1, const float* __restrict__ We2,
    const float* __restrict__ Wp1,
    unsigned short* __restrict__ Wg1, unsigned short* __restrict__ Wg2,
    unsigned short* __restrict__ Wgp1)
{
    int i = blockIdx.x * 256 + threadIdx.x;
    if (i < 4 * 64 * 128) {
        int k = i & 127, n = (i >> 7) & 63, l = i >> 13;
        Wg1[(size_t)(l * 64 + n) * 136 + k] = f2bf(We1[((size_t)l * 129 + k) * 64 + n]);
    }
    if (i < 4 * 64 * 64) {
        int h = i & 63, n = (i >> 6) & 63, l = i >> 12;
        Wg2[(size_t)(l * 64 + n) * 72 + h]  = f2bf(We2[((size_t)l * 64 + h) * 64 + n]);
        Wgp1[(size_t)(l * 64 + n) * 72 + h] = f2bf(Wp1[((size_t)l * 64 + h) * 64 + n]);
    }
}

// ---------------- weight prep: node weights ----------------
__global__ __launch_bounds__(256) void egnn_prep_wn(
    const float* __restrict__ Wn1, const float* __restrict__ Wn2,
    unsigned short* __restrict__ Wgn1, unsigned short* __restrict__ Wgn2)
{
    int i = blockIdx.x * 256 + threadIdx.x;
    if (i < 4 * 64 * 128) {
        int k = i & 127, n = (i >> 7) & 63, l = i >> 13;
        Wgn1[(size_t)(l * 64 + n) * 136 + k] = f2bf(Wn1[((size_t)l * 128 + k) * 64 + n]);
    }
    if (i < 4 * 64 * 64) {
        int h = i & 63, n = (i >> 6) & 63, l = i >> 12;
        Wgn2[(size_t)(l * 64 + n) * 72 + h] = f2bf(Wn2[((size_t)l * 64 + h) * 64 + n]);
    }
}

// ---------------- x0 -> bf16 ----------------
__global__ __launch_bounds__(256) void egnn_xbf(
    const float* __restrict__ x, unsigned short* __restrict__ xbf)
{
    int i = blockIdx.x * 256 + threadIdx.x;   // one float4 per thread
    if (i >= NN * 16) return;
    float4 v = ((const float4*)x)[i];
    ((uint2*)xbf)[i] = make_uint2(pk2(v.x, v.y), pk2(v.z, v.w));
}

// ---------------- edge MLP: multi-tile pipelined, bf16 MFMA --------
// 4 waves: eh=w>>1 (32-edge half), ch=w&1 (32-ch half). Double-buffered xls.
// MAT=true : m2 written to m2buf with 8 plain stores/wave (static vmem counts ->
//            counted bottom vmcnt excludes nothing important; no agg atomics).
// MAT=false: R11-proven atomic run-scan scatter, full vmcnt(0) drain before it.
template<bool POS, bool MAT>
__global__ __launch_bounds__(256) void egnn_edge(
    const unsigned short* __restrict__ xbf, const float* __restrict__ eD2,
    const int* __restrict__ eSrc, const int* __restrict__ eDst,
    const float* __restrict__ pos,
    const unsigned short* __restrict__ Wg1, const unsigned short* __restrict__ Wg2,
    const unsigned short* __restrict__ Wgp1,
    const float* __restrict__ We1,   // fp32, d2 row (row 128)
    const float* __restrict__ be1, const float* __restrict__ be2,
    const float* __restrict__ bp1, const float* __restrict__ Wp2,
    const float* __restrict__ bp2,
    float* __restrict__ agg, unsigned short* __restrict__ m2buf,
    float* __restrict__ dpos, int layer)
{
    // [xls0 16384][xls1 16384][m1l 9216][m2s 9216]
    __shared__ __align__(16) unsigned char pool[16384 * 2 + 9216 * 2];
    unsigned short* const xls0 = (unsigned short*)pool;
    unsigned short* const xls1 = (unsigned short*)(pool + 16384);
    unsigned short* const m1l  = (unsigned short*)(pool + 32768);
    unsigned short* const m2s  = (unsigned short*)(pool + 41984);

    const int t    = threadIdx.x;
    const int lane = t & 63;
    const int w    = t >> 6;
    const int l15  = lane & 15;
    const int g    = lane >> 4;
    const int g4   = g * 4;
    const int eh   = w >> 1;
    const int ch   = w & 1;
    const int er   = lane >> 4;          // gather: row within 4-row group
    const int half = (lane >> 3) & 1;    // gather: 0=dst-half, 1=src-half
    const int c    = lane & 7;           // gather: 16B chunk within half
    const int tile0 = blockIdx.x * TPB;
    const int wofs16 = __builtin_amdgcn_readfirstlane(w * 16);

    // ---- hoist loop-invariant weight fragments ----
    const unsigned short* W1b = &Wg1[(size_t)(layer * 64) * 136];
    const unsigned short* W2b = &Wg2[(size_t)(layer * 64) * 72];
    short8 w1f0[4], w1f1[4], w2f0[2], w2f1[2];
    #pragma unroll
    for (int ks = 0; ks < 4; ++ks) {
        w1f0[ks] = *(const short8*)&W1b[(ch * 32 +      l15) * 136 + ks * 32 + g * 8];
        w1f1[ks] = *(const short8*)&W1b[(ch * 32 + 16 + l15) * 136 + ks * 32 + g * 8];
    }
    #pragma unroll
    for (int ks = 0; ks < 2; ++ks) {
        w2f0[ks] = *(const short8*)&W2b[(ch * 32 +      l15) * 72 + ks * 32 + g * 8];
        w2f1[ks] = *(const short8*)&W2b[(ch * 32 + 16 + l15) * 72 + ks * 32 + g * 8];
    }
    float4 wrv[2], b1v[2], b2v[2];
    {
        const float* Wr = &We1[((size_t)layer * 129 + 128) * 64];
        const float* B1 = &be1[layer * 64];
        const float* B2 = &be2[layer * 64];
        #pragma unroll
        for (int nt = 0; nt < 2; ++nt) {
            int n0 = ch * 32 + nt * 16 + g * 4;
            wrv[nt] = *(const float4*)&Wr[n0];
            b1v[nt] = *(const float4*)&B1[n0];
            b2v[nt] = *(const float4*)&B2[n0];
        }
    }
    // pos-head constants
    float4 b1p[4], w2p[4];
    float bp2v = 0.f;
    if (POS) {
        #pragma unroll
        for (int m = 0; m < 4; ++m) {
            b1p[m] = *(const float4*)&bp1[(size_t)layer * 64 + m * 16 + g4];
            w2p[m] = *(const float4*)&Wp2[(size_t)layer * 64 + m * 16 + g4];
        }
        bp2v = bp2[layer];
    }

    const int* const ip = half ? eSrc : eDst;
    const int ebase = w * 16 + er;       // + i*4 ; (ebase+i*4)&7 == row&7

    // ---- prologue ----
    int nid[4];
    {
        const int gb0 = tile0 * 64;
        #pragma unroll
        for (int i = 0; i < 4; ++i) nid[i] = ip[gb0 + ebase + i * 4];
        #pragma unroll
        for (int i = 0; i < 4; ++i)
            gload_lds16(&xbf[(size_t)nid[i] * 64 + ((c ^ ((ebase + i * 4) & 7)) << 3)],
                        xls0 + w * 2048 + i * 512);
        SB();
        #pragma unroll
        for (int i = 0; i < 4; ++i) nid[i] = ip[gb0 + 64 + ebase + i * 4];
    }
    float d2c0 = eD2[tile0 * 64 + eh * 32 + l15];
    float d2c1 = eD2[tile0 * 64 + eh * 32 + 16 + l15];
    int pD = 0, pS = 0;
    if (POS) {
        pD = eDst[tile0 * 64 + wofs16 + l15];
        pS = eSrc[tile0 * 64 + wofs16 + l15];
    }
    SB();
    asm volatile("s_waitcnt vmcnt(0)" ::: "memory");
    SB();
    __builtin_amdgcn_s_barrier();
    SB();

    const f32x4 zero = {0.f, 0.f, 0.f, 0.f};

    for (int tt = 0; tt < TPB; ++tt) {
        const int b = tt & 1;
        unsigned short* const xcur = b ? xls1 : xls0;
        unsigned short* const xnxt = b ? xls0 : xls1;
        const int gb = (tile0 + tt) * 64;

        float d2n0 = 0.f, d2n1 = 0.f;
        int pDn = 0, pSn = 0;
        if (tt + 1 < TPB) {
            const int gb1 = gb + 64;
            #pragma unroll
            for (int i = 0; i < 4; ++i)
                gload_lds16(&xbf[(size_t)nid[i] * 64 + ((c ^ ((ebase + i * 4) & 7)) << 3)],
                            xnxt + w * 2048 + i * 512);
            SB();
            // static after-gather vector loads: d2 2 (+posidx 2) + nid refill 4
            d2n0 = eD2[gb1 + eh * 32 + l15];
            d2n1 = eD2[gb1 + eh * 32 + 16 + l15];
            if (POS) {
                pDn = eDst[gb1 + wofs16 + l15];
                pSn = eSrc[gb1 + wofs16 + l15];
            }
            const int gb2 = gb + 128;
            #pragma unroll
            for (int i = 0; i < 4; ++i) nid[i] = ip[gb2 + ebase + i * 4];
        }

        // GEMM1: D^T[n][e], K=128
        f32x4 a00 = zero, a01 = zero, a10 = zero, a11 = zero;
        {
            const int r0 = (eh * 32 + l15) * 128;
            const int r1 = r0 + 16 * 128;
            const int r7 = l15 & 7;
            #pragma unroll
            for (int ks = 0; ks < 4; ++ks) {
                int col = (((ks << 2) + g) ^ r7) << 3;
                short8 fb0 = *(const short8*)&xcur[r0 + col];
                short8 fb1 = *(const short8*)&xcur[r1 + col];
                a00 = __builtin_amdgcn_mfma_f32_16x16x32_bf16(w1f0[ks], fb0, a00, 0, 0, 0);
                a01 = __builtin_amdgcn_mfma_f32_16x16x32_bf16(w1f0[ks], fb1, a01, 0, 0, 0);
                a10 = __builtin_amdgcn_mfma_f32_16x16x32_bf16(w1f1[ks], fb0, a10, 0, 0, 0);
                a11 = __builtin_amdgcn_mfma_f32_16x16x32_bf16(w1f1[ks], fb1, a11, 0, 0, 0);
            }
        }
        // ep1: + d2 row + bias, SiLU, quantize -> m1l
        {
            int e0 = eh * 32 + l15;
            int e1 = e0 + 16;
            #pragma unroll
            for (int nt = 0; nt < 2; ++nt) {
                int n0 = ch * 32 + nt * 16 + g * 4;
                float4 wr = wrv[nt], bb = b1v[nt];
                f32x4 acc0 = nt ? a10 : a00;
                f32x4 acc1 = nt ? a11 : a01;
                float r0 = silu_f(acc0.x + d2c0 * wr.x + bb.x);
                float r1 = silu_f(acc0.y + d2c0 * wr.y + bb.y);
                float r2 = silu_f(acc0.z + d2c0 * wr.z + bb.z);
                float r3 = silu_f(acc0.w + d2c0 * wr.w + bb.w);
                *(uint2*)&m1l[e0 * 72 + n0] = make_uint2(pk2(r0, r1), pk2(r2, r3));
                r0 = silu_f(acc1.x + d2c1 * wr.x + bb.x);
                r1 = silu_f(acc1.y + d2c1 * wr.y + bb.y);
                r2 = silu_f(acc1.z + d2c1 * wr.z + bb.z);
                r3 = silu_f(acc1.w + d2c1 * wr.w + bb.w);
                *(uint2*)&m1l[e1 * 72 + n0] = make_uint2(pk2(r0, r1), pk2(r2, r3));
            }
        }
        // (E): m1l written
        asm volatile("s_waitcnt lgkmcnt(0)" ::: "memory");
        SB();
        __builtin_amdgcn_s_barrier();
        SB();

        // GEMM2: K=64
        f32x4 c00 = zero, c01 = zero, c10 = zero, c11 = zero;
        #pragma unroll
        for (int ks = 0; ks < 2; ++ks) {
            short8 fb0 = *(const short8*)&m1l[(eh * 32 +      l15) * 72 + ks * 32 + g * 8];
            short8 fb1 = *(const short8*)&m1l[(eh * 32 + 16 + l15) * 72 + ks * 32 + g * 8];
            c00 = __builtin_amdgcn_mfma_f32_16x16x32_bf16(w2f0[ks], fb0, c00, 0, 0, 0);
            c01 = __builtin_amdgcn_mfma_f32_16x16x32_bf16(w2f0[ks], fb1, c01, 0, 0, 0);
            c10 = __builtin_amdgcn_mfma_f32_16x16x32_bf16(w2f1[ks], fb0, c10, 0, 0, 0);
            c11 = __builtin_amdgcn_mfma_f32_16x16x32_bf16(w2f1[ks], fb1, c11, 0, 0, 0);
        }

        // ep2: + bias, SiLU -> m2s (bf16, separate buffer)
        {
            int e0 = eh * 32 + l15;
            int e1 = e0 + 16;
            #pragma unroll
            for (int nt = 0; nt < 2; ++nt) {
                int n0 = ch * 32 + nt * 16 + g * 4;
                float4 bb = b2v[nt];
                f32x4 acc0 = nt ? c10 : c00;
                f32x4 acc1 = nt ? c11 : c01;
                float r0 = silu_f(acc0.x + bb.x);
                float r1 = silu_f(acc0.y + bb.y);
                float r2 = silu_f(acc0.z + bb.z);
                float r3 = silu_f(acc0.w + bb.w);
                *(uint2*)&m2s[e0 * 72 + n0] = make_uint2(pk2(r0, r1), pk2(r2, r3));
                r0 = silu_f(acc1.x + bb.x);
                r1 = silu_f(acc1.y + bb.y);
                r2 = silu_f(acc1.z + bb.z);
                r3 = silu_f(acc1.w + bb.w);
                *(uint2*)&m2s[e1 * 72 + n0] = make_uint2(pk2(r0, r1), pk2(r2, r3));
            }
        }
        // (G): m2s visible to all waves
        asm volatile("s_waitcnt lgkmcnt(0)" ::: "memory");
        SB();
        __builtin_amdgcn_s_barrier();
        SB();

        if (POS) {
            // per-wave MFMA pos head over this wave's 16 edges
            f32x4 pa[4] = {zero, zero, zero, zero};
            const unsigned short* WPb = &Wgp1[(size_t)(layer * 64) * 72];
            #pragma unroll
            for (int ks = 0; ks < 2; ++ks) {
                short8 fb = *(const short8*)&m2s[(w * 16 + l15) * 72 + ks * 32 + g * 8];
                #pragma unroll
                for (int m = 0; m < 4; ++m) {
                    short8 wf = *(const short8*)&WPb[(size_t)(m * 16 + l15) * 72 + ks * 32 + g * 8];
                    pa[m] = __builtin_amdgcn_mfma_f32_16x16x32_bf16(wf, fb, pa[m], 0, 0, 0);
                }
            }
            float part = 0.0f;
            #pragma unroll
            for (int m = 0; m < 4; ++m) {
                part += silu_f(pa[m].x + b1p[m].x) * w2p[m].x;
                part += silu_f(pa[m].y + b1p[m].y) * w2p[m].y;
                part += silu_f(pa[m].z + b1p[m].z) * w2p[m].z;
                part += silu_f(pa[m].w + b1p[m].w) * w2p[m].w;
            }
            part += __shfl_xor(part, 16);
            part += __shfl_xor(part, 32);
            if (lane < 16) {
                float cv = part + bp2v;
                int d = pD, s = pS;
                float rx = pos[3*(size_t)d+0] - pos[3*(size_t)s+0];
                float ry = pos[3*(size_t)d+1] - pos[3*(size_t)s+1];
                float rz = pos[3*(size_t)d+2] - pos[3*(size_t)s+2];
                atomicAdd(&dpos[3*(size_t)d+0], rx * cv);
                atomicAdd(&dpos[3*(size_t)d+1], ry * cv);
                atomicAdd(&dpos[3*(size_t)d+2], rz * cv);
            }
        }

        if (MAT) {
            // 8 plain coalesced stores: rows w*16..+16 of this tile into m2buf.
            // lanes 0-31 -> row 2i, lanes 32-63 -> row 2i+1; 4B (2ch)/lane = 256B/store
            #pragma unroll
            for (int i = 0; i < 8; ++i) {
                int row = w * 16 + 2 * i + (lane >> 5);
                unsigned v = *(const unsigned*)&m2s[row * 72 + (lane & 31) * 2];
                *(unsigned*)&m2buf[(size_t)(gb + row) * 64 + (lane & 31) * 2] = v;
            }
        } else {
            // full drain, then R11-proven run-compressed atomic scatter
            SB();
            asm volatile("s_waitcnt vmcnt(0)" ::: "memory");
            SB();
            int dd[16];
            #pragma unroll
            for (int i = 0; i < 16; ++i) dd[i] = eDst[gb + wofs16 + i];
            float v[16];
            #pragma unroll
            for (int i = 0; i < 16; ++i) v[i] = bf2f(m2s[(w * 16 + i) * 72 + lane]);
            float run = v[0];
            int cur = dd[0];
            #pragma unroll
            for (int i = 1; i < 16; ++i) {
                if (dd[i] != cur) {
                    atomicAdd(&agg[(size_t)cur * 64 + lane], run);
                    run = 0.0f;
                    cur = dd[i];
                }
                run += v[i];
            }
            atomicAdd(&agg[(size_t)cur * 64 + lane], run);
        }

        if (tt + 1 < TPB) {
            d2c0 = d2n0; d2c1 = d2n1;
            if (POS) { pD = pDn; pS = pSn; }
            SB();
            if (MAT) {
                // counted: post-gather vector-ops = 14 (non-POS) / >=23 (POS);
                // N below that => gather(t+1) retired, stores/atomics float.
                if (POS) asm volatile("s_waitcnt vmcnt(20)" ::: "memory");
                else     asm volatile("s_waitcnt vmcnt(12)" ::: "memory");
            }
            SB();
            asm volatile("s_waitcnt lgkmcnt(0)" ::: "memory");
            SB();
            __builtin_amdgcn_s_barrier();
            SB();
        }
    }
}

// ---------------- node MLP via bf16 MFMA ----------------
// MAT=true: aggregate m2buf CSR rows (contiguous, coalesced) -> plane1.
// MAT=false: read prebuilt agg (R8-proven path).
template<bool WRITE_F32, bool MAT>
__global__ __launch_bounds__(256) void egnn_node_mfma(
    const unsigned short* __restrict__ xbf, const float* __restrict__ agg,
    const unsigned short* __restrict__ m2buf, const int* __restrict__ rowptr,
    const unsigned short* __restrict__ Wgn1, const unsigned short* __restrict__ Wgn2,
    const float* __restrict__ bn1, const float* __restrict__ bn2,
    float* __restrict__ xout, unsigned short* __restrict__ xbf_out, int layer)
{
    __shared__ __align__(16) unsigned char pool[16384 + 9216];
    unsigned short* const xpl = (unsigned short*)pool;
    unsigned short* const m1l = (unsigned short*)(pool + 16384);
    float* const          sXf = (float*)pool;

    const int t    = threadIdx.x;
    const int lane = t & 63;
    const int w    = t >> 6;
    const int l15  = lane & 15;
    const int g    = lane >> 4;
    const int eh   = w >> 1;
    const int ch   = w & 1;
    const int base = blockIdx.x * 64;
    const int nval = (NN - base < 64) ? (NN - base) : 64;

    // stage x-half via gload_lds (linear rows, source chunk-swizzled)
    #pragma unroll
    for (int i = 0; i < 2; ++i) {
        int e = w * 16 + i * 8 + (lane >> 3);
        int node = base + ((e < nval) ? e : 0);
        gload_lds16(&xbf[(size_t)node * 64 + (((lane & 7) ^ (e & 7)) << 3)],
                    xpl + w * 1024 + i * 512);
    }
    SB();

    const unsigned short* W1b = &Wgn1[(size_t)(layer * 64) * 136];
    const unsigned short* W2b = &Wgn2[(size_t)(layer * 64) * 72];
    short8 w1f0[4], w1f1[4], w2f0[2], w2f1[2];
    #pragma unroll
    for (int ks = 0; ks < 4; ++ks) {
        w1f0[ks] = *(const short8*)&W1b[(ch * 32 +      l15) * 136 + ks * 32 + g * 8];
        w1f1[ks] = *(const short8*)&W1b[(ch * 32 + 16 + l15) * 136 + ks * 32 + g * 8];
    }
    #pragma unroll
    for (int ks = 0; ks < 2; ++ks) {
        w2f0[ks] = *(const short8*)&W2b[(ch * 32 +      l15) * 72 + ks * 32 + g * 8];
        w2f1[ks] = *(const short8*)&W2b[(ch * 32 + 16 + l15) * 72 + ks * 32 + g * 8];
    }
    float4 b1v[2], b2v[2];
    {
        const float* B1 = &bn1[layer * 64];
        const float* B2 = &bn2[layer * 64];
        #pragma unroll
        for (int nt = 0; nt < 2; ++nt) {
            int n0 = ch * 32 + nt * 16 + g * 4;
            b1v[nt] = *(const float4*)&B1[n0];
            b2v[nt] = *(const float4*)&B2[n0];
        }
    }

    // stage agg-half -> plane1 (swizzled ds_write). thread (e = t>>2, q = t&3)
    {
        int e = t >> 2, q = t & 3;
        float acc[16];
        #pragma unroll
        for (int j = 0; j < 16; ++j) acc[j] = 0.0f;
        if (MAT) {
            if (e < nval) {
                int n = base + e;
                int r0 = rowptr[n], r1 = rowptr[n + 1];
                for (int r = r0; r < r1; ++r) {
                    uint4 u0 = *(const uint4*)&m2buf[(size_t)r * 64 + q * 16];
                    uint4 u1 = *(const uint4*)&m2buf[(size_t)r * 64 + q * 16 + 8];
                    acc[0]  += ulo(u0.x); acc[1]  += uhi(u0.x);
                    acc[2]  += ulo(u0.y); acc[3]  += uhi(u0.y);
                    acc[4]  += ulo(u0.z); acc[5]  += uhi(u0.z);
                    acc[6]  += ulo(u0.w); acc[7]  += uhi(u0.w);
                    acc[8]  += ulo(u1.x); acc[9]  += uhi(u1.x);
                    acc[10] += ulo(u1.y); acc[11] += uhi(u1.y);
                    acc[12] += ulo(u1.z); acc[13] += uhi(u1.z);
                    acc[14] += ulo(u1.w); acc[15] += uhi(u1.w);
                }
            }
        } else {
            int node = base + ((e < nval) ? e : 0);
            const float4* ap = (const float4*)&agg[(size_t)node * 64 + q * 16];
            float4 v0 = ap[0], v1 = ap[1], v2 = ap[2], v3 = ap[3];
            acc[0]=v0.x; acc[1]=v0.y; acc[2]=v0.z; acc[3]=v0.w;
            acc[4]=v1.x; acc[5]=v1.y; acc[6]=v1.z; acc[7]=v1.w;
            acc[8]=v2.x; acc[9]=v2.y; acc[10]=v2.z; acc[11]=v2.w;
            acc[12]=v3.x; acc[13]=v3.y; acc[14]=v3.z; acc[15]=v3.w;
        }
        uint4 u0, u1;
        u0.x = pk2(acc[0],  acc[1]);  u0.y = pk2(acc[2],  acc[3]);
        u0.z = pk2(acc[4],  acc[5]);  u0.w = pk2(acc[6],  acc[7]);
        u1.x = pk2(acc[8],  acc[9]);  u1.y = pk2(acc[10], acc[11]);
        u1.z = pk2(acc[12], acc[13]); u1.w = pk2(acc[14], acc[15]);
        *(uint4*)&xpl[4096 + e * 64 + (((2 * q)     ^ (e & 7)) << 3)] = u0;
        *(uint4*)&xpl[4096 + e * 64 + (((2 * q + 1) ^ (e & 7)) << 3)] = u1;
    }
    __syncthreads();   // full drain: gloads + ds_writes

    const f32x4 zero = {0.f, 0.f, 0.f, 0.f};
    f32x4 a00 = zero, a01 = zero, a10 = zero, a11 = zero;
    {
        const int e0 = eh * 32 + l15;
        const int e1 = e0 + 16;
        const int r7 = e0 & 7;
        #pragma unroll
        for (int ks = 0; ks < 4; ++ks) {
            int kc = (ks << 2) + g;
            int off0 = (kc >> 3) * 4096 + e0 * 64 + (((kc & 7) ^ r7) << 3);
            int off1 = (kc >> 3) * 4096 + e1 * 64 + (((kc & 7) ^ r7) << 3);
            short8 fb0 = *(const short8*)&xpl[off0];
            short8 fb1 = *(const short8*)&xpl[off1];
            a00 = __builtin_amdgcn_mfma_f32_16x16x32_bf16(w1f0[ks], fb0, a00, 0, 0, 0);
            a01 = __builtin_amdgcn_mfma_f32_16x16x32_bf16(w1f0[ks], fb1, a01, 0, 0, 0);
            a10 = __builtin_amdgcn_mfma_f32_16x16x32_bf16(w1f1[ks], fb0, a10, 0, 0, 0);
            a11 = __builtin_amdgcn_mfma_f32_16x16x32_bf16(w1f1[ks], fb1, a11, 0, 0, 0);
        }
    }
    {
        int e0 = eh * 32 + l15;
        int e1 = e0 + 16;
        #pragma unroll
        for (int nt = 0; nt < 2; ++nt) {
            int n0 = ch * 32 + nt * 16 + g * 4;
            float4 bb = b1v[nt];
            f32x4 acc0 = nt ? a10 : a00;
            f32x4 acc1 = nt ? a11 : a01;
            float r0 = silu_f(acc0.x + bb.x);
            float r1 = silu_f(acc0.y + bb.y);
            float r2 = silu_f(acc0.z + bb.z);
            float r3 = silu_f(acc0.w + bb.w);
            *(uint2*)&m1l[e0 * 72 + n0] = make_uint2(pk2(r0, r1), pk2(r2, r3));
            r0 = silu_f(acc1.x + bb.x);
            r1 = silu_f(acc1.y + bb.y);
            r2 = silu_f(acc1.z + bb.z);
            r3 = silu_f(acc1.w + bb.w);
            *(uint2*)&m1l[e1 * 72 + n0] = make_uint2(pk2(r0, r1), pk2(r2, r3));
        }
    }
    __syncthreads();

    f32x4 c00 = zero, c01 = zero, c10 = zero, c11 = zero;
    #pragma unroll
    for (int ks = 0; ks < 2; ++ks) {
        short8 fb0 = *(const short8*)&m1l[(eh * 32 +      l15) * 72 + ks * 32 + g * 8];
        short8 fb1 = *(const short8*)&m1l[(eh * 32 + 16 + l15) * 72 + ks * 32 + g * 8];
        c00 = __builtin_amdgcn_mfma_f32_16x16x32_bf16(w2f0[ks], fb0, c00, 0, 0, 0);
        c01 = __builtin_amdgcn_mfma_f32_16x16x32_bf16(w2f0[ks], fb1, c01, 0, 0, 0);
        c10 = __builtin_amdgcn_mfma_f32_16x16x32_bf16(w2f1[ks], fb0, c10, 0, 0, 0);
        c11 = __builtin_amdgcn_mfma_f32_16x16x32_bf16(w2f1[ks], fb1, c11, 0, 0, 0);
    }
    __syncthreads();   // m1l readers done -> sXf overlay safe

    {
        int e0 = eh * 32 + l15;
        int e1 = e0 + 16;
        #pragma unroll
        for (int nt = 0; nt < 2; ++nt) {
            int n0 = ch * 32 + nt * 16 + g * 4;
            float4 bb = b2v[nt];
            f32x4 acc0 = nt ? c10 : c00;
            f32x4 acc1 = nt ? c11 : c01;
            sXf[e0 * 65 + n0 + 0] = acc0.x + bb.x;
            sXf[e0 * 65 + n0 + 1] = acc0.y + bb.y;
            sXf[e0 * 65 + n0 + 2] = acc0.z + bb.z;
            sXf[e0 * 65 + n0 + 3] = acc0.w + bb.w;
            sXf[e1 * 65 + n0 + 0] = acc1.x + bb.x;
            sXf[e1 * 65 + n0 + 1] = acc1.y + bb.y;
            sXf[e1 * 65 + n0 + 2] = acc1.z + bb.z;
            sXf[e1 * 65 + n0 + 3] = acc1.w + bb.w;
        }
    }
    __syncthreads();

    if (WRITE_F32) {
        #pragma unroll
        for (int i = 0; i < 4; ++i) {
            int idx = i * 256 + t;
            int e = idx >> 4, c = idx & 15;
            if (e < nval) {
                float4 v;
                const float* p = &sXf[e * 65 + c * 4];
                v.x = p[0]; v.y = p[1]; v.z = p[2]; v.w = p[3];
                *reinterpret_cast<float4*>(&xout[(size_t)(base + e) * 64 + c * 4]) = v;
            }
        }
    }
    {
        int e = t >> 2, q = t & 3;
        if (e < nval) {
            const float* p = &sXf[e * 65 + q * 16];
            uint4 u0, u1;
            u0.x = pk2(p[0],  p[1]);  u0.y = pk2(p[2],  p[3]);
            u0.z = pk2(p[4],  p[5]);  u0.w = pk2(p[6],  p[7]);
            u1.x = pk2(p[8],  p[9]);  u1.y = pk2(p[10], p[11]);
            u1.z = pk2(p[12], p[13]); u1.w = pk2(p[14], p[15]);
            *(uint4*)&xbf_out[(size_t)(base + e) * 64 + q * 16 + 0] = u0;
            *(uint4*)&xbf_out[(size_t)(base + e) * 64 + q * 16 + 8] = u1;
        }
    }
}

// ---------------- finalize positions ----------------
__global__ __launch_bounds__(256) void egnn_final(
    const float* __restrict__ pos, const float* __restrict__ dpos,
    const int* __restrict__ rowptr, const float* __restrict__ logit,
    float* __restrict__ pos_out)
{
    int i = blockIdx.x * 256 + threadIdx.x;
    if (i >= NN * 3) return;
    int node = i / 3;
    float dg = fmaxf((float)(rowptr[node + 1] - rowptr[node]), 1.0f);
    float sig = 1.0f / (1.0f + __expf(-logit[0]));
    float upd = (dpos[i] / dg) * sig;
    upd = fminf(fmaxf(upd, -5.0f), 5.0f);
    float p = pos[i] + upd;
    pos_out[i] = fminf(fmaxf(p, -500.0f), 500.0f);
}

extern "C" void kernel_launch(void* const* d_in, const int* in_sizes, int n_in,
                              void* d_out, int out_size, void* d_ws, size_t ws_size,
                              hipStream_t stream)
{
    const float* x0    = (const float*)d_in[0];
    const float* pos   = (const float*)d_in[1];
    const int*   src   = (const int*)d_in[2];
    const int*   dst   = src + NE;
    const float* We1   = (const float*)d_in[3];
    const float* be1   = (const float*)d_in[4];
    const float* We2   = (const float*)d_in[5];
    const float* be2   = (const float*)d_in[6];
    const float* Wn1   = (const float*)d_in[7];
    const float* bn1   = (const float*)d_in[8];
    const float* Wn2   = (const float*)d_in[9];
    const float* bn2   = (const float*)d_in[10];
    const float* Wp1   = (const float*)d_in[11];
    const float* bp1   = (const float*)d_in[12];
    const float* Wp2   = (const float*)d_in[13];
    const float* bp2   = (const float*)d_in[14];
    const float* logit = (const float*)d_in[15];

    float* xout    = (float*)d_out;                 // [NN,64]
    float* pos_out = xout + (size_t)NN * 64;        // [NN,3]

    float* ws  = (float*)d_ws;
    float* agg  = ws;  ws += (size_t)NN * 64;
    float* dpos = ws;  ws += (size_t)NN * 3;
    float* eD2  = ws;  ws += NE;
    int* rowptr = (int*)ws;  ws += NN + 1;
    int* hc     = (int*)ws;  ws += NN;              // hist -> cursor
    int* eSrc   = (int*)ws;  ws += NE;
    int* eDst   = (int*)ws;  ws += NE;
    unsigned short* xbf = (unsigned short*)ws;      // [NN,64] bf16
    ws += (size_t)NN * 32;
    unsigned short* Wg1  = (unsigned short*)ws;     // 4*64*136
    unsigned short* Wg2  = Wg1 + 4 * 64 * 136;      // 4*64*72
    unsigned short* Wgn1 = Wg2 + 4 * 64 * 72;       // 4*64*136
    unsigned short* Wgn2 = Wgn1 + 4 * 64 * 136;     // 4*64*72
    unsigned short* Wgp1 = Wgn2 + 4 * 64 * 72;      // 4*64*72
    unsigned short* m2buf = Wgp1 + 4 * 64 * 72;     // [NE,64] bf16 (MAT mode)
    size_t needed = (size_t)((char*)(m2buf + (size_t)NE * 64) - (char*)d_ws);
    const bool mat = ws_size >= needed;

    hipMemsetAsync(hc, 0, NN * sizeof(int), stream);
    hipMemsetAsync(dpos, 0, (size_t)NN * 3 * sizeof(float), stream);
    egnn_hist<<<NE / 256, 256, 0, stream>>>(dst, hc);
    egnn_scan<<<1, 1024, 0, stream>>>(hc, rowptr);
    egnn_scatter<<<NE / 256, 256, 0, stream>>>(src, dst, pos, hc, eSrc, eDst, eD2);
    egnn_prep_w<<<128, 256, 0, stream>>>(We1, We2, Wp1, Wg1, Wg2, Wgp1);
    egnn_prep_wn<<<128, 256, 0, stream>>>(Wn1, Wn2, Wgn1, Wgn2);
    egnn_xbf<<<(NN * 16 + 255) / 256, 256, 0, stream>>>(x0, xbf);

    const int nblk = NTILES / TPB;                  // 1250
    const int nodeblk = (NN + 63) / 64;             // 782
    for (int l = 0; l < 4; ++l) {
        if (!mat) hipMemsetAsync(agg, 0, (size_t)NN * 64 * sizeof(float), stream);
        if (mat) {
            if (l == 3) {
                egnn_edge<true, true><<<nblk, 256, 0, stream>>>(
                    xbf, eD2, eSrc, eDst, pos, Wg1, Wg2, Wgp1, We1, be1, be2,
                    bp1, Wp2, bp2, agg, m2buf, dpos, l);
                egnn_node_mfma<true, true><<<nodeblk, 256, 0, stream>>>(
                    xbf, agg, m2buf, rowptr, Wgn1, Wgn2, bn1, bn2, xout, xbf, l);
            } else {
                egnn_edge<false, true><<<nblk, 256, 0, stream>>>(
                    xbf, eD2, eSrc, eDst, pos, Wg1, Wg2, Wgp1, We1, be1, be2,
                    bp1, Wp2, bp2, agg, m2buf, dpos, l);
                egnn_node_mfma<false, true><<<nodeblk, 256, 0, stream>>>(
                    xbf, agg, m2buf, rowptr, Wgn1, Wgn2, bn1, bn2, xout, xbf, l);
            }
        } else {
            if (l == 3) {
                egnn_edge<true, false><<<nblk, 256, 0, stream>>>(
                    xbf, eD2, eSrc, eDst, pos, Wg1, Wg2, Wgp1, We1, be1, be2,
                    bp1, Wp2, bp2, agg, m2buf, dpos, l);
                egnn_node_mfma<true, false><<<nodeblk, 256, 0, stream>>>(
                    xbf, agg, m2buf, rowptr, Wgn1, Wgn2, bn1, bn2, xout, xbf, l);
            } else {
                egnn_edge<false, false><<<nblk, 256, 0, stream>>>(
                    xbf, eD2, eSrc, eDst, pos, Wg1, Wg2, Wgp1, We1, be1, be2,
                    bp1, Wp2, bp2, agg, m2buf, dpos, l);
                egnn_node_mfma<false, false><<<nodeblk, 256, 0, stream>>>(
                    xbf, agg, m2buf, rowptr, Wgn1, Wgn2, bn1, bn2, xout, xbf, l);
            }
        }
    }
    egnn_final<<<(NN * 3 + 255) / 256, 256, 0, stream>>>(pos, dpos, rowptr, logit, pos_out);
}

// Round 14
// 852.308 us; speedup vs baseline: 1.6279x; 1.0300x over previous
//
#include <hip/hip_runtime.h>

#define NN 50000
#define NE 800000
#define NTILES 12500
#define TPB 10   // tiles (of 64 edges) per block; 12500 % 10 == 0 -> grid 1250

typedef __attribute__((ext_vector_type(8))) short short8;
typedef __attribute__((ext_vector_type(4))) float f32x4;

__device__ __forceinline__ float silu_f(float v) {
    return v / (1.0f + __expf(-v));
}
__device__ __forceinline__ unsigned short f2bf(float f) {
    unsigned u = __float_as_uint(f);
    u += 0x7fffu + ((u >> 16) & 1u);        // round-to-nearest-even
    return (unsigned short)(u >> 16);
}
__device__ __forceinline__ unsigned pk2(float a, float b) {
    return (unsigned)f2bf(a) | ((unsigned)f2bf(b) << 16);
}
__device__ __forceinline__ float bf2f(unsigned short v) {
    return __uint_as_float((unsigned)v << 16);
}
__device__ __forceinline__ void gload_lds16(const unsigned short* g, unsigned short* l) {
    __builtin_amdgcn_global_load_lds(
        (const __attribute__((address_space(1))) unsigned int*)g,
        (__attribute__((address_space(3))) unsigned int*)l, 16, 0, 0);
}
// lgkm-only barrier: drain LDS ops, leave vmcnt (in-flight gathers) alone
#define FENCE_BAR() do { \
    asm volatile("s_waitcnt lgkmcnt(0)" ::: "memory"); \
    __builtin_amdgcn_sched_barrier(0); \
    __builtin_amdgcn_s_barrier(); \
    __builtin_amdgcn_sched_barrier(0); \
} while (0)
// explicit full vmem drain (gathers landed); scheduler fence both sides
#define VMDRAIN() do { \
    __builtin_amdgcn_sched_barrier(0); \
    asm volatile("s_waitcnt vmcnt(0)" ::: "memory"); \
    __builtin_amdgcn_sched_barrier(0); \
} while (0)

// ---------------- CSR build: histogram of dst ----------------
__global__ __launch_bounds__(256) void egnn_hist(
    const int* __restrict__ dst, int* __restrict__ hc)
{
    int e = blockIdx.x * 256 + threadIdx.x;
    if (e < NE) atomicAdd(&hc[dst[e]], 1);
}

// ---------------- CSR build: exclusive scan (1 block, 1024 thr) ----------------
__global__ __launch_bounds__(1024) void egnn_scan(
    int* __restrict__ hc, int* __restrict__ rowptr)
{
    __shared__ int part[1024];
    const int t = threadIdx.x;
    const int C = (NN + 1023) / 1024;   // 49
    const int b0 = t * C;
    int s = 0;
    for (int i = 0; i < C; ++i) {
        int idx = b0 + i;
        if (idx < NN) s += hc[idx];
    }
    part[t] = s;
    __syncthreads();
    for (int off = 1; off < 1024; off <<= 1) {
        int v = (t >= off) ? part[t - off] : 0;
        __syncthreads();
        part[t] += v;
        __syncthreads();
    }
    int run = part[t] - s;              // exclusive base for this chunk
    for (int i = 0; i < C; ++i) {
        int idx = b0 + i;
        if (idx < NN) {
            int v = hc[idx];
            rowptr[idx] = run;
            hc[idx] = run;              // cursor init
            run += v;
        }
    }
    if (t == 1023) rowptr[NN] = part[1023];
}

// ---------------- CSR build: permute edges into dst-sorted order ----------------
__global__ __launch_bounds__(256) void egnn_scatter(
    const int* __restrict__ src, const int* __restrict__ dst,
    const float* __restrict__ pos, int* __restrict__ cursor,
    int* __restrict__ eSrc, int* __restrict__ eDst, float* __restrict__ eD2)
{
    int e = blockIdx.x * 256 + threadIdx.x;
    if (e >= NE) return;
    int s = src[e], d = dst[e];
    float rx = pos[3*d+0] - pos[3*s+0];
    float ry = pos[3*d+1] - pos[3*s+1];
    float rz = pos[3*d+2] - pos[3*s+2];
    int p = atomicAdd(&cursor[d], 1);
    eSrc[p] = s;
    eDst[p] = d;
    eD2[p]  = rx*rx + ry*ry + rz*rz;
}

// ---------------- weight prep: transpose + bf16-convert edge + pos weights --------
__global__ __launch_bounds__(256) void egnn_prep_w(
    const float* __restrict__ We1, const float* __restrict__ We2,
    const float* __restrict__ Wp1,
    unsigned short* __restrict__ Wg1, unsigned short* __restrict__ Wg2,
    unsigned short* __restrict__ Wgp1)
{
    int i = blockIdx.x * 256 + threadIdx.x;
    if (i < 4 * 64 * 128) {
        int k = i & 127, n = (i >> 7) & 63, l = i >> 13;
        Wg1[(size_t)(l * 64 + n) * 136 + k] = f2bf(We1[((size_t)l * 129 + k) * 64 + n]);
    }
    if (i < 4 * 64 * 64) {
        int h = i & 63, n = (i >> 6) & 63, l = i >> 12;
        Wg2[(size_t)(l * 64 + n) * 72 + h]  = f2bf(We2[((size_t)l * 64 + h) * 64 + n]);
        Wgp1[(size_t)(l * 64 + n) * 72 + h] = f2bf(Wp1[((size_t)l * 64 + h) * 64 + n]);
    }
}

// ---------------- weight prep: node weights ----------------
__global__ __launch_bounds__(256) void egnn_prep_wn(
    const float* __restrict__ Wn1, const float* __restrict__ Wn2,
    unsigned short* __restrict__ Wgn1, unsigned short* __restrict__ Wgn2)
{
    int i = blockIdx.x * 256 + threadIdx.x;
    if (i < 4 * 64 * 128) {
        int k = i & 127, n = (i >> 7) & 63, l = i >> 13;
        Wgn1[(size_t)(l * 64 + n) * 136 + k] = f2bf(Wn1[((size_t)l * 128 + k) * 64 + n]);
    }
    if (i < 4 * 64 * 64) {
        int h = i & 63, n = (i >> 6) & 63, l = i >> 12;
        Wgn2[(size_t)(l * 64 + n) * 72 + h] = f2bf(Wn2[((size_t)l * 64 + h) * 64 + n]);
    }
}

// ---------------- x0 -> bf16 ----------------
__global__ __launch_bounds__(256) void egnn_xbf(
    const float* __restrict__ x, unsigned short* __restrict__ xbf)
{
    int i = blockIdx.x * 256 + threadIdx.x;   // one float4 per thread
    if (i >= NN * 16) return;
    float4 v = ((const float4*)x)[i];
    ((uint2*)xbf)[i] = make_uint2(pk2(v.x, v.y), pk2(v.z, v.w));
}

// ---------------- edge MLP: multi-tile pipelined, bf16 MFMA (R11-proven) ----------
// TPB tiles of 64 edges per block. 4 waves: eh=w>>1 (32-edge half), ch=w&1 (32-ch half).
// Double-buffered xls; gather(t+1) issued at top, drained once per iter before scatter.
// m2 kept in separate bf16 buffer m2s (no overlay). Pos head = per-wave MFMA.
template<bool POS>
__global__ __launch_bounds__(256) void egnn_edge(
    const unsigned short* __restrict__ xbf, const float* __restrict__ eD2,
    const int* __restrict__ eSrc, const int* __restrict__ eDst,
    const float* __restrict__ pos,
    const unsigned short* __restrict__ Wg1, const unsigned short* __restrict__ Wg2,
    const unsigned short* __restrict__ Wgp1,
    const float* __restrict__ We1,   // fp32, d2 row (row 128)
    const float* __restrict__ be1, const float* __restrict__ be2,
    const float* __restrict__ bp1, const float* __restrict__ Wp2,
    const float* __restrict__ bp2,
    float* __restrict__ agg, float* __restrict__ dpos, int layer)
{
    // [xls0 16384][xls1 16384][m1l 9216][m2s 9216]
    __shared__ __align__(16) unsigned char pool[16384 * 2 + 9216 * 2];
    __shared__ int   sS[2][64];
    __shared__ int   sD[2][64];
    __shared__ float s2[2][64];

    unsigned short* const xls0 = (unsigned short*)pool;
    unsigned short* const xls1 = (unsigned short*)(pool + 16384);
    unsigned short* const m1l  = (unsigned short*)(pool + 32768);
    unsigned short* const m2s  = (unsigned short*)(pool + 41984);

    const int t    = threadIdx.x;
    const int lane = t & 63;
    const int w    = t >> 6;
    const int l15  = lane & 15;
    const int g    = lane >> 4;
    const int g4   = g * 4;
    const int eh   = w >> 1;
    const int ch   = w & 1;
    const int er   = lane >> 4;          // gather: row within 4-row group
    const int half = (lane >> 3) & 1;    // gather: 0=dst-half, 1=src-half
    const int c    = lane & 7;           // gather: 16B chunk within half
    const int tile0 = blockIdx.x * TPB;

    // ---- hoist loop-invariant weight fragments ----
    const unsigned short* W1b = &Wg1[(size_t)(layer * 64) * 136];
    const unsigned short* W2b = &Wg2[(size_t)(layer * 64) * 72];
    short8 w1f0[4], w1f1[4], w2f0[2], w2f1[2];
    #pragma unroll
    for (int ks = 0; ks < 4; ++ks) {
        w1f0[ks] = *(const short8*)&W1b[(ch * 32 +      l15) * 136 + ks * 32 + g * 8];
        w1f1[ks] = *(const short8*)&W1b[(ch * 32 + 16 + l15) * 136 + ks * 32 + g * 8];
    }
    #pragma unroll
    for (int ks = 0; ks < 2; ++ks) {
        w2f0[ks] = *(const short8*)&W2b[(ch * 32 +      l15) * 72 + ks * 32 + g * 8];
        w2f1[ks] = *(const short8*)&W2b[(ch * 32 + 16 + l15) * 72 + ks * 32 + g * 8];
    }
    float4 wrv[2], b1v[2], b2v[2];
    {
        const float* Wr = &We1[((size_t)layer * 129 + 128) * 64];
        const float* B1 = &be1[layer * 64];
        const float* B2 = &be2[layer * 64];
        #pragma unroll
        for (int nt = 0; nt < 2; ++nt) {
            int n0 = ch * 32 + nt * 16 + g * 4;
            wrv[nt] = *(const float4*)&Wr[n0];
            b1v[nt] = *(const float4*)&B1[n0];
            b2v[nt] = *(const float4*)&B2[n0];
        }
    }
    // pos-head constants (per-wave MFMA head): hoisted fp32 vectors
    float4 b1p[4], w2p[4];
    float bp2v = 0.f;
    if (POS) {
        #pragma unroll
        for (int m = 0; m < 4; ++m) {
            b1p[m] = *(const float4*)&bp1[(size_t)layer * 64 + m * 16 + g4];
            w2p[m] = *(const float4*)&Wp2[(size_t)layer * 64 + m * 16 + g4];
        }
        bp2v = bp2[layer];
    }

    const int* const ip = half ? eSrc : eDst;
    const int ebase = w * 16 + er;       // + i*4 ; (ebase+i*4)&7 == row&7

    // ---- prologue: gather tile0; prefetch idx(t1); stage(t0 -> LDS, t1 -> regs) ----
    int nid[4];
    {
        const int gb0 = tile0 * 64;
        #pragma unroll
        for (int i = 0; i < 4; ++i) nid[i] = ip[gb0 + ebase + i * 4];
        #pragma unroll
        for (int i = 0; i < 4; ++i)
            gload_lds16(&xbf[(size_t)nid[i] * 64 + ((c ^ ((ebase + i * 4) & 7)) << 3)],
                        xls0 + w * 2048 + i * 512);
        __builtin_amdgcn_sched_barrier(0);
        #pragma unroll
        for (int i = 0; i < 4; ++i) nid[i] = ip[gb0 + 64 + ebase + i * 4];
        if (t < 64) { sS[0][t] = eSrc[gb0 + t]; sD[0][t] = eDst[gb0 + t]; s2[0][t] = eD2[gb0 + t]; }
    }
    int stS = 0, stD = 0; float st2 = 0.f;
    if (t < 64) {
        const int gb1 = (tile0 + 1) * 64;
        stS = eSrc[gb1 + t]; stD = eDst[gb1 + t]; st2 = eD2[gb1 + t];
    }
    VMDRAIN();      // tile0 gather landed
    FENCE_BAR();    // stage LDS visible; all waves ready

    const f32x4 zero = {0.f, 0.f, 0.f, 0.f};

    for (int tt = 0; tt < TPB; ++tt) {
        const int b = tt & 1;
        unsigned short* const xcur = b ? xls1 : xls0;
        unsigned short* const xnxt = b ? xls0 : xls1;

        // (top) issue gather(t+1); refill nid(t+2)
        if (tt + 1 < TPB) {
            #pragma unroll
            for (int i = 0; i < 4; ++i)
                gload_lds16(&xbf[(size_t)nid[i] * 64 + ((c ^ ((ebase + i * 4) & 7)) << 3)],
                            xnxt + w * 2048 + i * 512);
            __builtin_amdgcn_sched_barrier(0);
            if (tt + 2 < TPB) {
                const int gb2 = (tile0 + tt + 2) * 64;
                #pragma unroll
                for (int i = 0; i < 4; ++i) nid[i] = ip[gb2 + ebase + i * 4];
            }
        }

        // GEMM1: D^T[n][e], K=128 (xcur ready via previous end-of-iter barrier)
        f32x4 a00 = zero, a01 = zero, a10 = zero, a11 = zero;
        {
            const int r0 = (eh * 32 + l15) * 128;
            const int r1 = r0 + 16 * 128;
            const int r7 = l15 & 7;
            __builtin_amdgcn_s_setprio(1);
            #pragma unroll
            for (int ks = 0; ks < 4; ++ks) {
                int col = (((ks << 2) + g) ^ r7) << 3;
                short8 fb0 = *(const short8*)&xcur[r0 + col];
                short8 fb1 = *(const short8*)&xcur[r1 + col];
                a00 = __builtin_amdgcn_mfma_f32_16x16x32_bf16(w1f0[ks], fb0, a00, 0, 0, 0);
                a01 = __builtin_amdgcn_mfma_f32_16x16x32_bf16(w1f0[ks], fb1, a01, 0, 0, 0);
                a10 = __builtin_amdgcn_mfma_f32_16x16x32_bf16(w1f1[ks], fb0, a10, 0, 0, 0);
                a11 = __builtin_amdgcn_mfma_f32_16x16x32_bf16(w1f1[ks], fb1, a11, 0, 0, 0);
            }
            __builtin_amdgcn_s_setprio(0);
        }
        // ep1: + d2 row + bias, SiLU, quantize -> m1l
        {
            float d2e0 = s2[b][eh * 32 + l15];
            float d2e1 = s2[b][eh * 32 + 16 + l15];
            int e0 = eh * 32 + l15;
            int e1 = e0 + 16;
            #pragma unroll
            for (int nt = 0; nt < 2; ++nt) {
                int n0 = ch * 32 + nt * 16 + g * 4;
                float4 wr = wrv[nt], bb = b1v[nt];
                f32x4 acc0 = nt ? a10 : a00;
                f32x4 acc1 = nt ? a11 : a01;
                float r0 = silu_f(acc0.x + d2e0 * wr.x + bb.x);
                float r1 = silu_f(acc0.y + d2e0 * wr.y + bb.y);
                float r2 = silu_f(acc0.z + d2e0 * wr.z + bb.z);
                float r3 = silu_f(acc0.w + d2e0 * wr.w + bb.w);
                *(uint2*)&m1l[e0 * 72 + n0] = make_uint2(pk2(r0, r1), pk2(r2, r3));
                r0 = silu_f(acc1.x + d2e1 * wr.x + bb.x);
                r1 = silu_f(acc1.y + d2e1 * wr.y + bb.y);
                r2 = silu_f(acc1.z + d2e1 * wr.z + bb.z);
                r3 = silu_f(acc1.w + d2e1 * wr.w + bb.w);
                *(uint2*)&m1l[e1 * 72 + n0] = make_uint2(pk2(r0, r1), pk2(r2, r3));
            }
        }
        FENCE_BAR();   // (E): m1l written

        // GEMM2: K=64
        f32x4 c00 = zero, c01 = zero, c10 = zero, c11 = zero;
        __builtin_amdgcn_s_setprio(1);
        #pragma unroll
        for (int ks = 0; ks < 2; ++ks) {
            short8 fb0 = *(const short8*)&m1l[(eh * 32 +      l15) * 72 + ks * 32 + g * 8];
            short8 fb1 = *(const short8*)&m1l[(eh * 32 + 16 + l15) * 72 + ks * 32 + g * 8];
            c00 = __builtin_amdgcn_mfma_f32_16x16x32_bf16(w2f0[ks], fb0, c00, 0, 0, 0);
            c01 = __builtin_amdgcn_mfma_f32_16x16x32_bf16(w2f0[ks], fb1, c01, 0, 0, 0);
            c10 = __builtin_amdgcn_mfma_f32_16x16x32_bf16(w2f1[ks], fb0, c10, 0, 0, 0);
            c11 = __builtin_amdgcn_mfma_f32_16x16x32_bf16(w2f1[ks], fb1, c11, 0, 0, 0);
        }
        __builtin_amdgcn_s_setprio(0);
        // (no (F) barrier: m2s is a separate buffer, not an overlay of m1l)

        // ep2: + bias, SiLU -> m2s (bf16); stage-write tile t+1; refill stage regs (t+2)
        {
            int e0 = eh * 32 + l15;
            int e1 = e0 + 16;
            #pragma unroll
            for (int nt = 0; nt < 2; ++nt) {
                int n0 = ch * 32 + nt * 16 + g * 4;
                float4 bb = b2v[nt];
                f32x4 acc0 = nt ? c10 : c00;
                f32x4 acc1 = nt ? c11 : c01;
                float r0 = silu_f(acc0.x + bb.x);
                float r1 = silu_f(acc0.y + bb.y);
                float r2 = silu_f(acc0.z + bb.z);
                float r3 = silu_f(acc0.w + bb.w);
                *(uint2*)&m2s[e0 * 72 + n0] = make_uint2(pk2(r0, r1), pk2(r2, r3));
                r0 = silu_f(acc1.x + bb.x);
                r1 = silu_f(acc1.y + bb.y);
                r2 = silu_f(acc1.z + bb.z);
                r3 = silu_f(acc1.w + bb.w);
                *(uint2*)&m2s[e1 * 72 + n0] = make_uint2(pk2(r0, r1), pk2(r2, r3));
            }
        }
        if (tt + 1 < TPB && t < 64) {
            sS[1 - b][t] = stS; sD[1 - b][t] = stD; s2[1 - b][t] = st2;
            if (tt + 2 < TPB) {
                const int gb2 = (tile0 + tt + 2) * 64;
                stS = eSrc[gb2 + t]; stD = eDst[gb2 + t]; st2 = eD2[gb2 + t];
            }
        }
        FENCE_BAR();   // (G): m2s + next-tile stage visible; also protects m1l reuse

        if (POS) {
            // per-wave MFMA pos head over this wave's 16 edges (w*16..+16)
            f32x4 pa[4] = {zero, zero, zero, zero};
            const unsigned short* WPb = &Wgp1[(size_t)(layer * 64) * 72];
            __builtin_amdgcn_s_setprio(1);
            #pragma unroll
            for (int ks = 0; ks < 2; ++ks) {
                short8 fb = *(const short8*)&m2s[(w * 16 + l15) * 72 + ks * 32 + g * 8];
                #pragma unroll
                for (int m = 0; m < 4; ++m) {
                    short8 wf = *(const short8*)&WPb[(size_t)(m * 16 + l15) * 72 + ks * 32 + g * 8];
                    pa[m] = __builtin_amdgcn_mfma_f32_16x16x32_bf16(wf, fb, pa[m], 0, 0, 0);
                }
            }
            __builtin_amdgcn_s_setprio(0);
            float part = 0.0f;
            #pragma unroll
            for (int m = 0; m < 4; ++m) {
                part += silu_f(pa[m].x + b1p[m].x) * w2p[m].x;
                part += silu_f(pa[m].y + b1p[m].y) * w2p[m].y;
                part += silu_f(pa[m].z + b1p[m].z) * w2p[m].z;
                part += silu_f(pa[m].w + b1p[m].w) * w2p[m].w;
            }
            part += __shfl_xor(part, 16);
            part += __shfl_xor(part, 32);
            if (lane < 16) {
                float cv = part + bp2v;
                int idx16 = w * 16 + lane;
                int d = sD[b][idx16], s = sS[b][idx16];
                float rx = pos[3*d+0] - pos[3*s+0];
                float ry = pos[3*d+1] - pos[3*s+1];
                float rz = pos[3*d+2] - pos[3*s+2];
                atomicAdd(&dpos[3*(size_t)d+0], rx * cv);
                atomicAdd(&dpos[3*(size_t)d+1], ry * cv);
                atomicAdd(&dpos[3*(size_t)d+2], rz * cv);
            }
        }

        // drain all vmem (incl. gather(t+1)) once per iteration
        VMDRAIN();

        // scatter: wave w owns edges [w*16, w*16+16), lane = channel; reads unrolled
        {
            const int e0 = w * 16;
            float v[16];
            #pragma unroll
            for (int i = 0; i < 16; ++i) v[i] = bf2f(m2s[(e0 + i) * 72 + lane]);
            int dd[16];
            #pragma unroll
            for (int i = 0; i < 16; ++i) dd[i] = sD[b][e0 + i];
            float run = v[0];
            int cur = dd[0];
            #pragma unroll
            for (int i = 1; i < 16; ++i) {
                if (dd[i] != cur) {
                    atomicAdd(&agg[(size_t)cur * 64 + lane], run);
                    run = 0.0f;
                    cur = dd[i];
                }
                run += v[i];
            }
            atomicAdd(&agg[(size_t)cur * 64 + lane], run);
        }
        FENCE_BAR();   // (END): scatter/pos LDS reads drained; next iter may overwrite
    }
}

// ---------------- node MLP via bf16 MFMA (R8-proven; FIN folds pos finalize) -------
template<bool FIN>
__global__ __launch_bounds__(256) void egnn_node_mfma(
    const unsigned short* __restrict__ xbf, const float* __restrict__ agg,
    const unsigned short* __restrict__ Wgn1, const unsigned short* __restrict__ Wgn2,
    const float* __restrict__ bn1, const float* __restrict__ bn2,
    float* __restrict__ xout, unsigned short* __restrict__ xbf_out,
    const float* __restrict__ pos, const float* __restrict__ dpos,
    const int* __restrict__ rowptr, const float* __restrict__ logit,
    float* __restrict__ pos_out, int layer)
{
    __shared__ __align__(16) unsigned char pool[16384 + 9216];
    unsigned short* const xpl = (unsigned short*)pool;
    unsigned short* const m1l = (unsigned short*)(pool + 16384);
    float* const          sXf = (float*)pool;

    const int t    = threadIdx.x;
    const int lane = t & 63;
    const int w    = t >> 6;
    const int l15  = lane & 15;
    const int g    = lane >> 4;
    const int eh   = w >> 1;
    const int ch   = w & 1;
    const int base = blockIdx.x * 64;
    const int nval = (NN - base < 64) ? (NN - base) : 64;

    // stage x-half via gload_lds (linear rows, source chunk-swizzled)
    #pragma unroll
    for (int i = 0; i < 2; ++i) {
        int e = w * 16 + i * 8 + (lane >> 3);
        int node = base + ((e < nval) ? e : 0);
        gload_lds16(&xbf[(size_t)node * 64 + (((lane & 7) ^ (e & 7)) << 3)],
                    xpl + w * 1024 + i * 512);
    }
    __builtin_amdgcn_sched_barrier(0);

    const unsigned short* W1b = &Wgn1[(size_t)(layer * 64) * 136];
    const unsigned short* W2b = &Wgn2[(size_t)(layer * 64) * 72];
    short8 w1f0[4], w1f1[4], w2f0[2], w2f1[2];
    #pragma unroll
    for (int ks = 0; ks < 4; ++ks) {
        w1f0[ks] = *(const short8*)&W1b[(ch * 32 +      l15) * 136 + ks * 32 + g * 8];
        w1f1[ks] = *(const short8*)&W1b[(ch * 32 + 16 + l15) * 136 + ks * 32 + g * 8];
    }
    #pragma unroll
    for (int ks = 0; ks < 2; ++ks) {
        w2f0[ks] = *(const short8*)&W2b[(ch * 32 +      l15) * 72 + ks * 32 + g * 8];
        w2f1[ks] = *(const short8*)&W2b[(ch * 32 + 16 + l15) * 72 + ks * 32 + g * 8];
    }
    float4 b1v[2], b2v[2];
    {
        const float* B1 = &bn1[layer * 64];
        const float* B2 = &bn2[layer * 64];
        #pragma unroll
        for (int nt = 0; nt < 2; ++nt) {
            int n0 = ch * 32 + nt * 16 + g * 4;
            b1v[nt] = *(const float4*)&B1[n0];
            b2v[nt] = *(const float4*)&B2[n0];
        }
    }

    // stage agg-half: fp32 read + pk2 -> plane1 (swizzled ds_write)
    {
        int e = t >> 2, q = t & 3;
        int node = base + ((e < nval) ? e : 0);
        const float4* ap = (const float4*)&agg[(size_t)node * 64 + q * 16];
        float4 v0 = ap[0], v1 = ap[1], v2 = ap[2], v3 = ap[3];
        uint4 u0, u1;
        u0.x = pk2(v0.x, v0.y); u0.y = pk2(v0.z, v0.w);
        u0.z = pk2(v1.x, v1.y); u0.w = pk2(v1.z, v1.w);
        u1.x = pk2(v2.x, v2.y); u1.y = pk2(v2.z, v2.w);
        u1.z = pk2(v3.x, v3.y); u1.w = pk2(v3.z, v3.w);
        *(uint4*)&xpl[4096 + e * 64 + (((2 * q)     ^ (e & 7)) << 3)] = u0;
        *(uint4*)&xpl[4096 + e * 64 + (((2 * q + 1) ^ (e & 7)) << 3)] = u1;
    }
    __syncthreads();   // full drain: gloads + ds_writes

    const f32x4 zero = {0.f, 0.f, 0.f, 0.f};
    f32x4 a00 = zero, a01 = zero, a10 = zero, a11 = zero;
    {
        const int e0 = eh * 32 + l15;
        const int e1 = e0 + 16;
        const int r7 = e0 & 7;
        __builtin_amdgcn_s_setprio(1);
        #pragma unroll
        for (int ks = 0; ks < 4; ++ks) {
            int kc = (ks << 2) + g;
            int off0 = (kc >> 3) * 4096 + e0 * 64 + (((kc & 7) ^ r7) << 3);
            int off1 = (kc >> 3) * 4096 + e1 * 64 + (((kc & 7) ^ r7) << 3);
            short8 fb0 = *(const short8*)&xpl[off0];
            short8 fb1 = *(const short8*)&xpl[off1];
            a00 = __builtin_amdgcn_mfma_f32_16x16x32_bf16(w1f0[ks], fb0, a00, 0, 0, 0);
            a01 = __builtin_amdgcn_mfma_f32_16x16x32_bf16(w1f0[ks], fb1, a01, 0, 0, 0);
            a10 = __builtin_amdgcn_mfma_f32_16x16x32_bf16(w1f1[ks], fb0, a10, 0, 0, 0);
            a11 = __builtin_amdgcn_mfma_f32_16x16x32_bf16(w1f1[ks], fb1, a11, 0, 0, 0);
        }
        __builtin_amdgcn_s_setprio(0);
    }
    {
        int e0 = eh * 32 + l15;
        int e1 = e0 + 16;
        #pragma unroll
        for (int nt = 0; nt < 2; ++nt) {
            int n0 = ch * 32 + nt * 16 + g * 4;
            float4 bb = b1v[nt];
            f32x4 acc0 = nt ? a10 : a00;
            f32x4 acc1 = nt ? a11 : a01;
            float r0 = silu_f(acc0.x + bb.x);
            float r1 = silu_f(acc0.y + bb.y);
            float r2 = silu_f(acc0.z + bb.z);
            float r3 = silu_f(acc0.w + bb.w);
            *(uint2*)&m1l[e0 * 72 + n0] = make_uint2(pk2(r0, r1), pk2(r2, r3));
            r0 = silu_f(acc1.x + bb.x);
            r1 = silu_f(acc1.y + bb.y);
            r2 = silu_f(acc1.z + bb.z);
            r3 = silu_f(acc1.w + bb.w);
            *(uint2*)&m1l[e1 * 72 + n0] = make_uint2(pk2(r0, r1), pk2(r2, r3));
        }
    }
    __syncthreads();

    f32x4 c00 = zero, c01 = zero, c10 = zero, c11 = zero;
    __builtin_amdgcn_s_setprio(1);
    #pragma unroll
    for (int ks = 0; ks < 2; ++ks) {
        short8 fb0 = *(const short8*)&m1l[(eh * 32 +      l15) * 72 + ks * 32 + g * 8];
        short8 fb1 = *(const short8*)&m1l[(eh * 32 + 16 + l15) * 72 + ks * 32 + g * 8];
        c00 = __builtin_amdgcn_mfma_f32_16x16x32_bf16(w2f0[ks], fb0, c00, 0, 0, 0);
        c01 = __builtin_amdgcn_mfma_f32_16x16x32_bf16(w2f0[ks], fb1, c01, 0, 0, 0);
        c10 = __builtin_amdgcn_mfma_f32_16x16x32_bf16(w2f1[ks], fb0, c10, 0, 0, 0);
        c11 = __builtin_amdgcn_mfma_f32_16x16x32_bf16(w2f1[ks], fb1, c11, 0, 0, 0);
    }
    __builtin_amdgcn_s_setprio(0);
    __syncthreads();   // m1l readers done -> sXf overlay safe

    {
        int e0 = eh * 32 + l15;
        int e1 = e0 + 16;
        #pragma unroll
        for (int nt = 0; nt < 2; ++nt) {
            int n0 = ch * 32 + nt * 16 + g * 4;
            float4 bb = b2v[nt];
            f32x4 acc0 = nt ? c10 : c00;
            f32x4 acc1 = nt ? c11 : c01;
            sXf[e0 * 65 + n0 + 0] = acc0.x + bb.x;
            sXf[e0 * 65 + n0 + 1] = acc0.y + bb.y;
            sXf[e0 * 65 + n0 + 2] = acc0.z + bb.z;
            sXf[e0 * 65 + n0 + 3] = acc0.w + bb.w;
            sXf[e1 * 65 + n0 + 0] = acc1.x + bb.x;
            sXf[e1 * 65 + n0 + 1] = acc1.y + bb.y;
            sXf[e1 * 65 + n0 + 2] = acc1.z + bb.z;
            sXf[e1 * 65 + n0 + 3] = acc1.w + bb.w;
        }
    }
    __syncthreads();

    if (FIN) {
        // fp32 x output (final layer)
        #pragma unroll
        for (int i = 0; i < 4; ++i) {
            int idx = i * 256 + t;
            int e = idx >> 4, c = idx & 15;
            if (e < nval) {
                float4 v;
                const float* p = &sXf[e * 65 + c * 4];
                v.x = p[0]; v.y = p[1]; v.z = p[2]; v.w = p[3];
                *reinterpret_cast<float4*>(&xout[(size_t)(base + e) * 64 + c * 4]) = v;
            }
        }
        // folded position finalize: 64 nodes x 3 comps = 192 threads
        if (t < 192) {
            int e = t / 3, comp = t % 3;
            if (e < nval) {
                int node = base + e;
                size_t i = (size_t)node * 3 + comp;
                float dg = fmaxf((float)(rowptr[node + 1] - rowptr[node]), 1.0f);
                float sig = 1.0f / (1.0f + __expf(-logit[0]));
                float upd = (dpos[i] / dg) * sig;
                upd = fminf(fmaxf(upd, -5.0f), 5.0f);
                float p = pos[i] + upd;
                pos_out[i] = fminf(fmaxf(p, -500.0f), 500.0f);
            }
        }
    } else {
        // bf16 export for next layer
        int e = t >> 2, q = t & 3;
        if (e < nval) {
            const float* p = &sXf[e * 65 + q * 16];
            uint4 u0, u1;
            u0.x = pk2(p[0],  p[1]);  u0.y = pk2(p[2],  p[3]);
            u0.z = pk2(p[4],  p[5]);  u0.w = pk2(p[6],  p[7]);
            u1.x = pk2(p[8],  p[9]);  u1.y = pk2(p[10], p[11]);
            u1.z = pk2(p[12], p[13]); u1.w = pk2(p[14], p[15]);
            *(uint4*)&xbf_out[(size_t)(base + e) * 64 + q * 16 + 0] = u0;
            *(uint4*)&xbf_out[(size_t)(base + e) * 64 + q * 16 + 8] = u1;
        }
    }
}

extern "C" void kernel_launch(void* const* d_in, const int* in_sizes, int n_in,
                              void* d_out, int out_size, void* d_ws, size_t ws_size,
                              hipStream_t stream)
{
    const float* x0    = (const float*)d_in[0];
    const float* pos   = (const float*)d_in[1];
    const int*   src   = (const int*)d_in[2];
    const int*   dst   = src + NE;
    const float* We1   = (const float*)d_in[3];
    const float* be1   = (const float*)d_in[4];
    const float* We2   = (const float*)d_in[5];
    const float* be2   = (const float*)d_in[6];
    const float* Wn1   = (const float*)d_in[7];
    const float* bn1   = (const float*)d_in[8];
    const float* Wn2   = (const float*)d_in[9];
    const float* bn2   = (const float*)d_in[10];
    const float* Wp1   = (const float*)d_in[11];
    const float* bp1   = (const float*)d_in[12];
    const float* Wp2   = (const float*)d_in[13];
    const float* bp2   = (const float*)d_in[14];
    const float* logit = (const float*)d_in[15];

    float* xout    = (float*)d_out;                 // [NN,64]
    float* pos_out = xout + (size_t)NN * 64;        // [NN,3]

    float* ws  = (float*)d_ws;
    float* agg  = ws;  ws += (size_t)NN * 64;
    float* dpos = ws;  ws += (size_t)NN * 3;
    float* eD2  = ws;  ws += NE;
    int* rowptr = (int*)ws;  ws += NN + 1;
    int* hc     = (int*)ws;  ws += NN;              // hist -> cursor
    int* eSrc   = (int*)ws;  ws += NE;
    int* eDst   = (int*)ws;  ws += NE;
    unsigned short* xbf = (unsigned short*)ws;      // [NN,64] bf16
    ws += (size_t)NN * 32;
    unsigned short* Wg1  = (unsigned short*)ws;     // 4*64*136
    unsigned short* Wg2  = Wg1 + 4 * 64 * 136;      // 4*64*72
    unsigned short* Wgn1 = Wg2 + 4 * 64 * 72;       // 4*64*136
    unsigned short* Wgn2 = Wgn1 + 4 * 64 * 136;     // 4*64*72
    unsigned short* Wgp1 = Wgn2 + 4 * 64 * 72;      // 4*64*72

    hipMemsetAsync(hc, 0, NN * sizeof(int), stream);
    hipMemsetAsync(dpos, 0, (size_t)NN * 3 * sizeof(float), stream);
    egnn_hist<<<NE / 256, 256, 0, stream>>>(dst, hc);
    egnn_scan<<<1, 1024, 0, stream>>>(hc, rowptr);
    egnn_scatter<<<NE / 256, 256, 0, stream>>>(src, dst, pos, hc, eSrc, eDst, eD2);
    egnn_prep_w<<<128, 256, 0, stream>>>(We1, We2, Wp1, Wg1, Wg2, Wgp1);
    egnn_prep_wn<<<128, 256, 0, stream>>>(Wn1, Wn2, Wgn1, Wgn2);
    egnn_xbf<<<(NN * 16 + 255) / 256, 256, 0, stream>>>(x0, xbf);

    const int nblk = NTILES / TPB;                  // 1250
    const int nodeblk = (NN + 63) / 64;             // 782
    for (int l = 0; l < 4; ++l) {
        hipMemsetAsync(agg, 0, (size_t)NN * 64 * sizeof(float), stream);
        if (l == 3) {
            egnn_edge<true><<<nblk, 256, 0, stream>>>(
                xbf, eD2, eSrc, eDst, pos, Wg1, Wg2, Wgp1, We1, be1, be2,
                bp1, Wp2, bp2, agg, dpos, l);
            egnn_node_mfma<true><<<nodeblk, 256, 0, stream>>>(
                xbf, agg, Wgn1, Wgn2, bn1, bn2, xout, xbf,
                pos, dpos, rowptr, logit, pos_out, l);
        } else {
            egnn_edge<false><<<nblk, 256, 0, stream>>>(
                xbf, eD2, eSrc, eDst, pos, Wg1, Wg2, Wgp1, We1, be1, be2,
                bp1, Wp2, bp2, agg, dpos, l);
            egnn_node_mfma<false><<<nodeblk, 256, 0, stream>>>(
                xbf, agg, Wgn1, Wgn2, bn1, bn2, xout, xbf,
                pos, dpos, rowptr, logit, pos_out, l);
        }
    }
}